// Round 6
// baseline (195.410 us; speedup 1.0000x reference)
//
#include <hip/hip_runtime.h>

#define CH 128
#define BN_EPS 1e-5f

typedef unsigned int uint32;
typedef unsigned short ushort16;
using f32x4  = __attribute__((ext_vector_type(4))) float;
using bf16x8 = __attribute__((ext_vector_type(8))) short;

__device__ __forceinline__ ushort16 f2b(float f) {
    uint32 u = __float_as_uint(f);
    return (ushort16)((u + 0x7FFFu + ((u >> 16) & 1u)) >> 16);   // RNE
}
__device__ __forceinline__ float blo(uint32 u) { return __uint_as_float(u << 16); }
__device__ __forceinline__ float bhi(uint32 u) { return __uint_as_float(u & 0xFFFF0000u); }

// ---------------------------------------------------------------------------
// Fused prep kernel (grid = 3125 blocks x 256):
//  (a) edge-chain build with H=4 sub-chains per node:
//      head[(d<<2)|(e&3)] <- atomicExch, pair[e] = {next, src}.
//      Shorter chains (avg 4 vs 16) => 2.5x shorter serial critical path in
//      the aggregate walk. int64-vs-int32 detect inline via ballot.
//  (b) x f32 -> xb bf16 (8 elems/thread)
//  (c) blocks [0,128): WcT[co][k] bf16 build (k<128 -> Wr, k>=128 -> Wl)
//  (d) block 0: zero bn[0:256]
__global__ __launch_bounds__(256) void sage_prep(
    const float* __restrict__ x, const void* __restrict__ ei,
    const float* __restrict__ Wl, const float* __restrict__ Wr,
    int* __restrict__ head, int2* __restrict__ pair,
    uint32* __restrict__ xb4, ushort16* __restrict__ wct,
    float* __restrict__ bn, int nEdges, int total8)
{
    const int* pi = (const int*)ei;
    int lane = threadIdx.x & 63;
    int probe = pi[lane * 2 + 1];
    bool is64 = (__ballot(probe != 0) == 0ULL);

    int e = blockIdx.x * 256 + threadIdx.x;
    if (e < nEdges) {
        int s, d;
        if (is64) {
            const long long* p = (const long long*)ei;
            s = (int)p[e];
            d = (int)p[nEdges + e];
        } else {
            s = pi[e];
            d = pi[nEdges + e];
        }
        int old = atomicExch(&head[(d << 2) | (e & 3)], e);
        pair[e] = make_int2(old, s);
    }

    int i = blockIdx.x * 256 + threadIdx.x;
    if (i < total8) {
        const float4* x4 = (const float4*)x;
        float4 a = x4[2 * i], b = x4[2 * i + 1];
        uint4 o;
        o.x = (uint32)f2b(a.x) | ((uint32)f2b(a.y) << 16);
        o.y = (uint32)f2b(a.z) | ((uint32)f2b(a.w) << 16);
        o.z = (uint32)f2b(b.x) | ((uint32)f2b(b.y) << 16);
        o.w = (uint32)f2b(b.z) | ((uint32)f2b(b.w) << 16);
        ((uint4*)xb4)[i] = o;
    }

    if (blockIdx.x < 128) {
        int idx = blockIdx.x * 256 + threadIdx.x;    // covers 128*256 = CH*256
        int co = idx >> 8, k = idx & 255;
        float v = (k < 128) ? Wr[co * 128 + k] : Wl[co * 128 + (k - 128)];
        wct[idx] = f2b(v);
    }
    if (blockIdx.x == 0) bn[threadIdx.x] = 0.f;      // bn_sum[128] + bn_sumsq[128]
}

// ---------------------------------------------------------------------------
// Chain-walk gather: ONE node per wave (50000 waves - full TLP), walking the
// node's 4 sub-chains interleaved (4x MLP per wave). Heads come in as one
// coalesced int4. Per step: up to 4 independent 8B pair loads + 4 independent
// coalesced 256B row gathers from L2/L3-resident xb.
__global__ __launch_bounds__(256) void sage_aggregate(
    const ushort16* __restrict__ xb, const int* __restrict__ head,
    const int2* __restrict__ pair, uint32* __restrict__ mean_b, int nNodes)
{
    int node = blockIdx.x * 4 + (threadIdx.x >> 6);
    if (node >= nNodes) return;
    int lane = threadIdx.x & 63;

    int4 h4 = *(const int4*)(head + ((size_t)node << 2));
    int cur[4] = {h4.x, h4.y, h4.z, h4.w};
    float ax[4] = {0.f, 0.f, 0.f, 0.f}, ay[4] = {0.f, 0.f, 0.f, 0.f};
    int cnt[4] = {0, 0, 0, 0};

    while (cur[0] >= 0 || cur[1] >= 0 || cur[2] >= 0 || cur[3] >= 0) {
        int2 pr[4];
        #pragma unroll
        for (int c = 0; c < 4; ++c)
            if (cur[c] >= 0) pr[c] = pair[cur[c]];
        #pragma unroll
        for (int c = 0; c < 4; ++c) {
            if (cur[c] >= 0) {
                uint32 u = *(const uint32*)((const char*)xb + ((size_t)pr[c].y << 8) + lane * 4);
                ax[c] += blo(u);
                ay[c] += bhi(u);
                ++cnt[c];
                cur[c] = pr[c].x;
            }
        }
    }

    float tot = (float)((cnt[0] + cnt[1]) + (cnt[2] + cnt[3]));
    float inv = 1.0f / fmaxf(tot, 1.0f);
    float sx = (ax[0] + ax[1]) + (ax[2] + ax[3]);
    float sy = (ay[0] + ay[1]) + (ay[2] + ay[3]);
    uint32 o = (uint32)f2b(sx * inv) | ((uint32)f2b(sy * inv) << 16);
    mean_b[(size_t)node * (CH / 2) + lane] = o;
}

// ---------------------------------------------------------------------------
// h[n][co] = sum_k Xc[n][k] * WcT[co][k] + bl[co], Xc = [xb | mean_b] (K=256).
// MFMA 16x16x32 bf16. Block = 256 thr = 4 waves x 16 rows = 64 rows, all 128 co.
// Fused BN partials -> one atomicAdd per channel per block.
__global__ __launch_bounds__(256) void sage_gemm(
    const ushort16* __restrict__ xb, const ushort16* __restrict__ mean_b,
    const ushort16* __restrict__ wct, const float* __restrict__ bl,
    float* __restrict__ h, float* __restrict__ bn, int nNodes)
{
    __shared__ float redS[4][CH];
    __shared__ float redQ[4][CH];

    int tid = threadIdx.x;
    int wave = tid >> 6, lane = tid & 63;
    int col = lane & 15, kg = lane >> 4;
    int rowBase = blockIdx.x * 64 + wave * 16;

    int arow = min(rowBase + col, nNodes - 1);          // A-frag row = lane&15
    const ushort16* xrow = xb + (size_t)arow * CH;
    const ushort16* mrow = mean_b + (size_t)arow * CH;

    f32x4 acc[8];
    #pragma unroll
    for (int cb = 0; cb < 8; ++cb) acc[cb] = (f32x4){0.f, 0.f, 0.f, 0.f};

    #pragma unroll
    for (int kstep = 0; kstep < 8; ++kstep) {
        const ushort16* asrc = (kstep < 4) ? (xrow + kstep * 32 + kg * 8)
                                           : (mrow + (kstep - 4) * 32 + kg * 8);
        bf16x8 a = *(const bf16x8*)asrc;
        #pragma unroll
        for (int cb = 0; cb < 8; ++cb) {
            const ushort16* bsrc = wct + (size_t)(cb * 16 + col) * 256 + kstep * 32 + kg * 8;
            bf16x8 b = *(const bf16x8*)bsrc;
            acc[cb] = __builtin_amdgcn_mfma_f32_16x16x32_bf16(a, b, acc[cb], 0, 0, 0);
        }
    }

    // epilogue: bias, store h, BN partial sums
    #pragma unroll
    for (int cb = 0; cb < 8; ++cb) {
        int co = cb * 16 + col;
        float blv = bl[co];
        float s = 0.f, ss = 0.f;
        #pragma unroll
        for (int j = 0; j < 4; ++j) {
            int r = rowBase + kg * 4 + j;               // C row = (lane>>4)*4+j
            float v = acc[cb][j] + blv;
            if (r < nNodes) {
                h[(size_t)r * CH + co] = v;
                s += v;
                ss += v * v;
            }
        }
        s  += __shfl_xor(s, 16);  s  += __shfl_xor(s, 32);
        ss += __shfl_xor(ss, 16); ss += __shfl_xor(ss, 32);
        if (kg == 0) { redS[wave][co] = s; redQ[wave][co] = ss; }
    }
    __syncthreads();
    if (tid < CH) {
        atomicAdd(&bn[tid], redS[0][tid] + redS[1][tid] + redS[2][tid] + redS[3][tid]);
    } else {
        int c = tid - CH;
        atomicAdd(&bn[CH + c], redQ[0][c] + redQ[1][c] + redQ[2][c] + redQ[3][c]);
    }
}

// ---------------------------------------------------------------------------
// Fused BN-finalize + apply: every block recomputes scale/shift from bn sums
// (128-wide, ~1us of redundant VALU), then normalizes+ReLUs its h slice.
__global__ __launch_bounds__(256) void sage_apply(
    float* __restrict__ h, const float* __restrict__ bn,
    const float* __restrict__ gamma, const float* __restrict__ beta,
    int total4, int nNodes)
{
    __shared__ float sc_sh[CH], sh_sh[CH];
    int tid = threadIdx.x;
    if (tid < CH) {
        float invN = 1.0f / (float)nNodes;
        float mu = bn[tid] * invN;
        float var = fmaxf(bn[CH + tid] * invN - mu * mu, 0.f);
        float sc = gamma[tid] * rsqrtf(var + BN_EPS);
        sc_sh[tid] = sc;
        sh_sh[tid] = beta[tid] - mu * sc;
    }
    __syncthreads();
    int i = blockIdx.x * 256 + tid;
    if (i >= total4) return;
    float4 v = reinterpret_cast<float4*>(h)[i];
    int c = (i * 4) & 127;
    float4 sc = *reinterpret_cast<const float4*>(&sc_sh[c]);
    float4 sh = *reinterpret_cast<const float4*>(&sh_sh[c]);
    v.x = fmaxf(fmaf(v.x, sc.x, sh.x), 0.f);
    v.y = fmaxf(fmaf(v.y, sc.y, sh.y), 0.f);
    v.z = fmaxf(fmaf(v.z, sc.z, sh.z), 0.f);
    v.w = fmaxf(fmaf(v.w, sc.w, sh.w), 0.f);
    reinterpret_cast<float4*>(h)[i] = v;
}

// ---------------------------------------------------------------------------
extern "C" void kernel_launch(void* const* d_in, const int* in_sizes, int n_in,
                              void* d_out, int out_size, void* d_ws, size_t ws_size,
                              hipStream_t stream)
{
    const float* x     = (const float*)d_in[0];
    const void*  ei    = d_in[1];
    const float* Wl    = (const float*)d_in[2];
    const float* bl    = (const float*)d_in[3];
    const float* Wr    = (const float*)d_in[4];
    const float* gamma = (const float*)d_in[5];
    const float* beta  = (const float*)d_in[6];

    int nNodes = in_sizes[0] / CH;
    int nEdges = in_sizes[1] / 2;
    int nBlkM  = (nNodes + 63) / 64;

    // ws layout (256B-aligned slabs)
    char* p = (char*)d_ws;
    auto take = [&](size_t bytes) {
        char* r = p;
        p += (bytes + 255) & ~(size_t)255;
        return r;
    };
    ushort16* xb      = (ushort16*)take((size_t)nNodes * CH * 2);      // 12.8 MB
    ushort16* mean_b  = (ushort16*)take((size_t)nNodes * CH * 2);      // 12.8 MB
    ushort16* wct     = (ushort16*)take((size_t)CH * 256 * 2);         // 64 KB
    int*      head    = (int*)take((size_t)nNodes * 4 * 4);            // H=4, memset 0xFF
    float*    bn      = (float*)take(256 * 4);                         // zeroed in prep
    int2*     pair    = (int2*)take((size_t)nEdges * 8);               // 6.4 MB

    float* h = (float*)d_out;

    hipMemsetAsync(head, 0xFF, (size_t)nNodes * 4 * 4, stream);        // head = -1

    int total8 = nNodes * CH / 8;
    int eBlocks = (nEdges + 255) / 256;
    int pBlocks = max(eBlocks, (total8 + 255) / 256);
    sage_prep<<<pBlocks, 256, 0, stream>>>(
        x, ei, Wl, Wr, head, pair, (uint32*)xb, wct, bn, nEdges, total8);

    sage_aggregate<<<(nNodes + 3) / 4, 256, 0, stream>>>(
        xb, head, pair, (uint32*)mean_b, nNodes);

    sage_gemm<<<nBlkM, 256, 0, stream>>>(
        xb, mean_b, wct, bl, h, bn, nNodes);

    int total4 = nNodes * CH / 4;
    sage_apply<<<(total4 + 255) / 256, 256, 0, stream>>>(
        h, bn, gamma, beta, total4, nNodes);
}

// Round 7
// 182.794 us; speedup vs baseline: 1.0690x; 1.0690x over previous
//
#include <hip/hip_runtime.h>

#define CH 128
#define BN_EPS 1e-5f

typedef unsigned int uint32;
typedef unsigned short ushort16;
using f32x4  = __attribute__((ext_vector_type(4))) float;
using bf16x8 = __attribute__((ext_vector_type(8))) short;

__device__ __forceinline__ ushort16 f2b(float f) {
    uint32 u = __float_as_uint(f);
    return (ushort16)((u + 0x7FFFu + ((u >> 16) & 1u)) >> 16);   // RNE
}
__device__ __forceinline__ float blo(uint32 u) { return __uint_as_float(u << 16); }
__device__ __forceinline__ float bhi(uint32 u) { return __uint_as_float(u & 0xFFFF0000u); }

// ---------------------------------------------------------------------------
// Fused prep kernel (grid = 3125 blocks x 256):
//  (a) edge-chain build: head[d] <- atomicExch, pair[e] = {next, src}
//      (int64-vs-int32 detect inline via ballot over first 64 odd words)
//  (b) x f32 -> xb bf16 (GEMM operand) AND xq fp8-e4m3 (aggregate gather
//      operand, 128B/row = 2 cache lines vs bf16's 4 -> fewer outstanding
//      lines on the latency-bound gather path)
//  (c) blocks [0,128): WcT[co][k] bf16 build (k<128 -> Wr, k>=128 -> Wl)
//  (d) block 0: zero bn[0:256]
__global__ __launch_bounds__(256) void sage_prep(
    const float* __restrict__ x, const void* __restrict__ ei,
    const float* __restrict__ Wl, const float* __restrict__ Wr,
    int* __restrict__ head, int2* __restrict__ pair,
    uint32* __restrict__ xb4, uint2* __restrict__ xq8,
    ushort16* __restrict__ wct, float* __restrict__ bn,
    int nEdges, int total8)
{
    const int* pi = (const int*)ei;
    int lane = threadIdx.x & 63;
    int probe = pi[lane * 2 + 1];
    bool is64 = (__ballot(probe != 0) == 0ULL);

    int e = blockIdx.x * 256 + threadIdx.x;
    if (e < nEdges) {
        int s, d;
        if (is64) {
            const long long* p = (const long long*)ei;
            s = (int)p[e];
            d = (int)p[nEdges + e];
        } else {
            s = pi[e];
            d = pi[nEdges + e];
        }
        int old = atomicExch(&head[d], e);
        pair[e] = make_int2(old, s);
    }

    int i = blockIdx.x * 256 + threadIdx.x;
    if (i < total8) {
        const float4* x4 = (const float4*)x;
        float4 a = x4[2 * i], b = x4[2 * i + 1];
        uint4 o;
        o.x = (uint32)f2b(a.x) | ((uint32)f2b(a.y) << 16);
        o.y = (uint32)f2b(a.z) | ((uint32)f2b(a.w) << 16);
        o.z = (uint32)f2b(b.x) | ((uint32)f2b(b.y) << 16);
        o.w = (uint32)f2b(b.z) | ((uint32)f2b(b.w) << 16);
        ((uint4*)xb4)[i] = o;

        int qa = __builtin_amdgcn_cvt_pk_fp8_f32(a.x, a.y, 0, false);
        qa = __builtin_amdgcn_cvt_pk_fp8_f32(a.z, a.w, qa, true);
        int qb = __builtin_amdgcn_cvt_pk_fp8_f32(b.x, b.y, 0, false);
        qb = __builtin_amdgcn_cvt_pk_fp8_f32(b.z, b.w, qb, true);
        xq8[i] = make_uint2((uint32)qa, (uint32)qb);
    }

    if (blockIdx.x < 128) {
        int idx = blockIdx.x * 256 + threadIdx.x;    // covers 128*256 = CH*256
        int co = idx >> 8, k = idx & 255;
        float v = (k < 128) ? Wr[co * 128 + k] : Wl[co * 128 + (k - 128)];
        wct[idx] = f2b(v);
    }
    if (blockIdx.x == 0) bn[threadIdx.x] = 0.f;      // bn_sum[128] + bn_sumsq[128]
}

// ---------------------------------------------------------------------------
// Chain-walk gather (R5 structure: 4 full-node chains interleaved per wave),
// now gathering fp8 rows: per edge one 128B coalesced load (2 lines) decoded
// via v_cvt_f32_fp8, accumulated in f32. Lane l covers channels {2l, 2l+1}.
__global__ __launch_bounds__(256) void sage_aggregate(
    const char* __restrict__ xq, const int* __restrict__ head,
    const int2* __restrict__ pair, uint32* __restrict__ mean_b, int nNodes)
{
    int wid = blockIdx.x * 4 + (threadIdx.x >> 6);
    int nbase = wid * 4;
    if (nbase >= nNodes) return;
    int lane = threadIdx.x & 63;

    float ax[4] = {0.f, 0.f, 0.f, 0.f}, ay[4] = {0.f, 0.f, 0.f, 0.f};
    int cur[4], cnt[4] = {0, 0, 0, 0};
    #pragma unroll
    for (int c = 0; c < 4; ++c)
        cur[c] = (nbase + c < nNodes) ? head[nbase + c] : -1;

    while (cur[0] >= 0 || cur[1] >= 0 || cur[2] >= 0 || cur[3] >= 0) {
        int2 pr[4];
        #pragma unroll
        for (int c = 0; c < 4; ++c)
            if (cur[c] >= 0) pr[c] = pair[cur[c]];
        #pragma unroll
        for (int c = 0; c < 4; ++c) {
            if (cur[c] >= 0) {
                int q = (int)*(const unsigned short*)(xq + ((size_t)pr[c].y << 7) + lane * 2);
                ax[c] += __builtin_amdgcn_cvt_f32_fp8(q, 0);
                ay[c] += __builtin_amdgcn_cvt_f32_fp8(q, 1);
                ++cnt[c];
                cur[c] = pr[c].x;
            }
        }
    }

    #pragma unroll
    for (int c = 0; c < 4; ++c) {
        int n = nbase + c;
        if (n < nNodes) {
            float inv = 1.0f / fmaxf((float)cnt[c], 1.0f);
            uint32 o = (uint32)f2b(ax[c] * inv) | ((uint32)f2b(ay[c] * inv) << 16);
            mean_b[(size_t)n * (CH / 2) + lane] = o;
        }
    }
}

// ---------------------------------------------------------------------------
// h[n][co] = sum_k Xc[n][k] * WcT[co][k] + bl[co], Xc = [xb | mean_b] (K=256).
// MFMA 16x16x32 bf16. Block = 256 thr = 4 waves x 16 rows = 64 rows, all 128 co.
// Fused BN partials -> one atomicAdd per channel per block.
__global__ __launch_bounds__(256) void sage_gemm(
    const ushort16* __restrict__ xb, const ushort16* __restrict__ mean_b,
    const ushort16* __restrict__ wct, const float* __restrict__ bl,
    float* __restrict__ h, float* __restrict__ bn, int nNodes)
{
    __shared__ float redS[4][CH];
    __shared__ float redQ[4][CH];

    int tid = threadIdx.x;
    int wave = tid >> 6, lane = tid & 63;
    int col = lane & 15, kg = lane >> 4;
    int rowBase = blockIdx.x * 64 + wave * 16;

    int arow = min(rowBase + col, nNodes - 1);          // A-frag row = lane&15
    const ushort16* xrow = xb + (size_t)arow * CH;
    const ushort16* mrow = mean_b + (size_t)arow * CH;

    f32x4 acc[8];
    #pragma unroll
    for (int cb = 0; cb < 8; ++cb) acc[cb] = (f32x4){0.f, 0.f, 0.f, 0.f};

    #pragma unroll
    for (int kstep = 0; kstep < 8; ++kstep) {
        const ushort16* asrc = (kstep < 4) ? (xrow + kstep * 32 + kg * 8)
                                           : (mrow + (kstep - 4) * 32 + kg * 8);
        bf16x8 a = *(const bf16x8*)asrc;
        #pragma unroll
        for (int cb = 0; cb < 8; ++cb) {
            const ushort16* bsrc = wct + (size_t)(cb * 16 + col) * 256 + kstep * 32 + kg * 8;
            bf16x8 b = *(const bf16x8*)bsrc;
            acc[cb] = __builtin_amdgcn_mfma_f32_16x16x32_bf16(a, b, acc[cb], 0, 0, 0);
        }
    }

    // epilogue: bias, store h, BN partial sums
    #pragma unroll
    for (int cb = 0; cb < 8; ++cb) {
        int co = cb * 16 + col;
        float blv = bl[co];
        float s = 0.f, ss = 0.f;
        #pragma unroll
        for (int j = 0; j < 4; ++j) {
            int r = rowBase + kg * 4 + j;               // C row = (lane>>4)*4+j
            float v = acc[cb][j] + blv;
            if (r < nNodes) {
                h[(size_t)r * CH + co] = v;
                s += v;
                ss += v * v;
            }
        }
        s  += __shfl_xor(s, 16);  s  += __shfl_xor(s, 32);
        ss += __shfl_xor(ss, 16); ss += __shfl_xor(ss, 32);
        if (kg == 0) { redS[wave][co] = s; redQ[wave][co] = ss; }
    }
    __syncthreads();
    if (tid < CH) {
        atomicAdd(&bn[tid], redS[0][tid] + redS[1][tid] + redS[2][tid] + redS[3][tid]);
    } else {
        int c = tid - CH;
        atomicAdd(&bn[CH + c], redQ[0][c] + redQ[1][c] + redQ[2][c] + redQ[3][c]);
    }
}

// ---------------------------------------------------------------------------
// Fused BN-finalize + apply: every block recomputes scale/shift from bn sums
// (128-wide, ~1us of redundant VALU), then normalizes+ReLUs its h slice.
__global__ __launch_bounds__(256) void sage_apply(
    float* __restrict__ h, const float* __restrict__ bn,
    const float* __restrict__ gamma, const float* __restrict__ beta,
    int total4, int nNodes)
{
    __shared__ float sc_sh[CH], sh_sh[CH];
    int tid = threadIdx.x;
    if (tid < CH) {
        float invN = 1.0f / (float)nNodes;
        float mu = bn[tid] * invN;
        float var = fmaxf(bn[CH + tid] * invN - mu * mu, 0.f);
        float sc = gamma[tid] * rsqrtf(var + BN_EPS);
        sc_sh[tid] = sc;
        sh_sh[tid] = beta[tid] - mu * sc;
    }
    __syncthreads();
    int i = blockIdx.x * 256 + tid;
    if (i >= total4) return;
    float4 v = reinterpret_cast<float4*>(h)[i];
    int c = (i * 4) & 127;
    float4 sc = *reinterpret_cast<const float4*>(&sc_sh[c]);
    float4 sh = *reinterpret_cast<const float4*>(&sh_sh[c]);
    v.x = fmaxf(fmaf(v.x, sc.x, sh.x), 0.f);
    v.y = fmaxf(fmaf(v.y, sc.y, sh.y), 0.f);
    v.z = fmaxf(fmaf(v.z, sc.z, sh.z), 0.f);
    v.w = fmaxf(fmaf(v.w, sc.w, sh.w), 0.f);
    reinterpret_cast<float4*>(h)[i] = v;
}

// ---------------------------------------------------------------------------
extern "C" void kernel_launch(void* const* d_in, const int* in_sizes, int n_in,
                              void* d_out, int out_size, void* d_ws, size_t ws_size,
                              hipStream_t stream)
{
    const float* x     = (const float*)d_in[0];
    const void*  ei    = d_in[1];
    const float* Wl    = (const float*)d_in[2];
    const float* bl    = (const float*)d_in[3];
    const float* Wr    = (const float*)d_in[4];
    const float* gamma = (const float*)d_in[5];
    const float* beta  = (const float*)d_in[6];

    int nNodes = in_sizes[0] / CH;
    int nEdges = in_sizes[1] / 2;
    int nBlkM  = (nNodes + 63) / 64;

    // ws layout (256B-aligned slabs)
    char* p = (char*)d_ws;
    auto take = [&](size_t bytes) {
        char* r = p;
        p += (bytes + 255) & ~(size_t)255;
        return r;
    };
    ushort16* xb      = (ushort16*)take((size_t)nNodes * CH * 2);      // 12.8 MB
    char*     xq      = (char*)take((size_t)nNodes * CH);              // 6.4 MB fp8
    ushort16* mean_b  = (ushort16*)take((size_t)nNodes * CH * 2);      // 12.8 MB
    ushort16* wct     = (ushort16*)take((size_t)CH * 256 * 2);         // 64 KB
    int*      head    = (int*)take((size_t)nNodes * 4);                // memset 0xFF
    float*    bn      = (float*)take(256 * 4);                         // zeroed in prep
    int2*     pair    = (int2*)take((size_t)nEdges * 8);               // 6.4 MB

    float* h = (float*)d_out;

    hipMemsetAsync(head, 0xFF, (size_t)nNodes * 4, stream);            // head = -1

    int total8 = nNodes * CH / 8;
    int eBlocks = (nEdges + 255) / 256;
    int pBlocks = max(eBlocks, (total8 + 255) / 256);
    sage_prep<<<pBlocks, 256, 0, stream>>>(
        x, ei, Wl, Wr, head, pair, (uint32*)xb, (uint2*)xq, wct, bn,
        nEdges, total8);

    int aBlocks = ((nNodes + 3) / 4 + 3) / 4;   // 4 nodes/wave, 4 waves/block
    sage_aggregate<<<aBlocks, 256, 0, stream>>>(
        xq, head, pair, (uint32*)mean_b, nNodes);

    sage_gemm<<<nBlkM, 256, 0, stream>>>(
        xb, mean_b, wct, bl, h, bn, nNodes);

    int total4 = nNodes * CH / 4;
    sage_apply<<<(total4 + 255) / 256, 256, 0, stream>>>(
        h, bn, gamma, beta, total4, nNodes);
}

// Round 8
// 150.562 us; speedup vs baseline: 1.2979x; 1.2141x over previous
//
#include <hip/hip_runtime.h>

#define CH 128
#define BN_EPS 1e-5f

typedef unsigned int uint32;
typedef unsigned short ushort16;
using f32x4  = __attribute__((ext_vector_type(4))) float;
using bf16x8 = __attribute__((ext_vector_type(8))) short;

__device__ __forceinline__ ushort16 f2b(float f) {
    uint32 u = __float_as_uint(f);
    return (ushort16)((u + 0x7FFFu + ((u >> 16) & 1u)) >> 16);   // RNE
}

// ---------------------------------------------------------------------------
// Fused prep kernel (grid = 3125 blocks x 256):
//  (a) edge-chain build: head[d] <- atomicExch, pair[e] = {next, src}
//      (int64-vs-int32 detect inline via ballot over first 64 odd words)
//  (b) x f32 -> xb bf16 (GEMM operand) AND xq fp8-e4m3 (gather operand)
//  (c) blocks [0,128): WcT[co][k] bf16 build (k<128 -> Wr, k>=128 -> Wl)
//  (d) block 0: zero bn[0:256]; block 1: zero the fp8 zero-row (index nNodes)
__global__ __launch_bounds__(256) void sage_prep(
    const float* __restrict__ x, const void* __restrict__ ei,
    const float* __restrict__ Wl, const float* __restrict__ Wr,
    int* __restrict__ head, int2* __restrict__ pair,
    uint32* __restrict__ xb4, uint2* __restrict__ xq8,
    ushort16* __restrict__ wct, float* __restrict__ bn,
    int nEdges, int total8)
{
    const int* pi = (const int*)ei;
    int lane = threadIdx.x & 63;
    int probe = pi[lane * 2 + 1];
    bool is64 = (__ballot(probe != 0) == 0ULL);

    int e = blockIdx.x * 256 + threadIdx.x;
    if (e < nEdges) {
        int s, d;
        if (is64) {
            const long long* p = (const long long*)ei;
            s = (int)p[e];
            d = (int)p[nEdges + e];
        } else {
            s = pi[e];
            d = pi[nEdges + e];
        }
        int old = atomicExch(&head[d], e);
        pair[e] = make_int2(old, s);
    }

    int i = blockIdx.x * 256 + threadIdx.x;
    if (i < total8) {
        const float4* x4 = (const float4*)x;
        float4 a = x4[2 * i], b = x4[2 * i + 1];
        uint4 o;
        o.x = (uint32)f2b(a.x) | ((uint32)f2b(a.y) << 16);
        o.y = (uint32)f2b(a.z) | ((uint32)f2b(a.w) << 16);
        o.z = (uint32)f2b(b.x) | ((uint32)f2b(b.y) << 16);
        o.w = (uint32)f2b(b.z) | ((uint32)f2b(b.w) << 16);
        ((uint4*)xb4)[i] = o;

        int qa = __builtin_amdgcn_cvt_pk_fp8_f32(a.x, a.y, 0, false);
        qa = __builtin_amdgcn_cvt_pk_fp8_f32(a.z, a.w, qa, true);
        int qb = __builtin_amdgcn_cvt_pk_fp8_f32(b.x, b.y, 0, false);
        qb = __builtin_amdgcn_cvt_pk_fp8_f32(b.z, b.w, qb, true);
        xq8[i] = make_uint2((uint32)qa, (uint32)qb);
    }

    if (blockIdx.x < 128) {
        int idx = blockIdx.x * 256 + threadIdx.x;    // covers 128*256 = CH*256
        int co = idx >> 8, k = idx & 255;
        float v = (k < 128) ? Wr[co * 128 + k] : Wl[co * 128 + (k - 128)];
        wct[idx] = f2b(v);
    }
    if (blockIdx.x == 0) bn[threadIdx.x] = 0.f;      // bn_sum[128] + bn_sumsq[128]
    if (blockIdx.x == 1 && threadIdx.x < 32)         // fp8 zero-row at index total8/16... = nNodes
        ((uint32*)(xq8))[(size_t)total8 * 2 + threadIdx.x] = 0;   // total8*8B = nNodes*CH bytes
}

// ---------------------------------------------------------------------------
// Chain-walk gather, instruction-economized:
//  - 4 chains per wave; walker state (cur, cnt) lives in lanes 0-3.
//  - ONE masked 8B gather loads pair[] for all 4 chains (was 4 instrs);
//    next-pointer lands in the walker lane directly.
//  - TWO packed row gathers: lanes 0-31 read chain0/2's fp8 row (4B/lane),
//    lanes 32-63 chain1/3's. 3 VMEM instrs per 4 edges (was 8).
//  - Finished chains redirect to a zeroed row at index nNodes (branchless).
// Lane l (l&31) covers channels 4(l&31)..4(l&31)+3 via cvt_f32_fp8 sel 0-3.
__global__ __launch_bounds__(256) void sage_aggregate(
    const char* __restrict__ xq, const int* __restrict__ head,
    const int2* __restrict__ pair, uint32* __restrict__ mean_b, int nNodes)
{
    int wid = blockIdx.x * 4 + (threadIdx.x >> 6);
    int nbase = wid * 4;
    if (nbase >= nNodes) return;
    int lane = threadIdx.x & 63;
    int half = lane >> 5;            // 0: chains 0/2, 1: chains 1/3
    int sub = lane & 31;

    const int ZROW = nNodes;         // zeroed fp8 row

    int cur = -1;
    if (lane < 4) {
        int n = nbase + lane;
        cur = (n < nNodes) ? head[n] : -1;
    }
    int cnt = 0;
    float4 accA = {0.f, 0.f, 0.f, 0.f};   // chain (half)   : 0 or 1
    float4 accB = {0.f, 0.f, 0.f, 0.f};   // chain (2+half) : 2 or 3

    while (__ballot(cur >= 0) != 0ULL) {
        int2 pr = make_int2(-1, ZROW);
        if (cur >= 0) pr = pair[cur];                 // 1 VMEM for 4 chains
        int s0 = __shfl(pr.y, 0), s1 = __shfl(pr.y, 1);
        int s2 = __shfl(pr.y, 2), s3 = __shfl(pr.y, 3);

        int sA = half ? s1 : s0;
        int sB = half ? s3 : s2;
        uint32 uA = *(const uint32*)(xq + ((size_t)sA << 7) + sub * 4);
        uint32 uB = *(const uint32*)(xq + ((size_t)sB << 7) + sub * 4);

        accA.x += __builtin_amdgcn_cvt_f32_fp8(uA, 0);
        accA.y += __builtin_amdgcn_cvt_f32_fp8(uA, 1);
        accA.z += __builtin_amdgcn_cvt_f32_fp8(uA, 2);
        accA.w += __builtin_amdgcn_cvt_f32_fp8(uA, 3);
        accB.x += __builtin_amdgcn_cvt_f32_fp8(uB, 0);
        accB.y += __builtin_amdgcn_cvt_f32_fp8(uB, 1);
        accB.z += __builtin_amdgcn_cvt_f32_fp8(uB, 2);
        accB.w += __builtin_amdgcn_cvt_f32_fp8(uB, 3);

        if (cur >= 0) { ++cnt; cur = pr.x; }
    }

    // counts: chain c's length sits in lane c
    int cA = __shfl(cnt, half);          // 0 or 1
    int cB = __shfl(cnt, 2 + half);      // 2 or 3
    float invA = 1.0f / fmaxf((float)cA, 1.0f);
    float invB = 1.0f / fmaxf((float)cB, 1.0f);

    // store: row-major bf16, lane sub covers channels 4*sub..4*sub+3 (8B)
    int nA = nbase + half;
    if (nA < nNodes) {
        uint2 o;
        o.x = (uint32)f2b(accA.x * invA) | ((uint32)f2b(accA.y * invA) << 16);
        o.y = (uint32)f2b(accA.z * invA) | ((uint32)f2b(accA.w * invA) << 16);
        *(uint2*)((char*)mean_b + (size_t)nA * 256 + sub * 8) = o;
    }
    int nB = nbase + 2 + half;
    if (nB < nNodes) {
        uint2 o;
        o.x = (uint32)f2b(accB.x * invB) | ((uint32)f2b(accB.y * invB) << 16);
        o.y = (uint32)f2b(accB.z * invB) | ((uint32)f2b(accB.w * invB) << 16);
        *(uint2*)((char*)mean_b + (size_t)nB * 256 + sub * 8) = o;
    }
}

// ---------------------------------------------------------------------------
// h[n][co] = sum_k Xc[n][k] * WcT[co][k] + bl[co], Xc = [xb | mean_b] (K=256).
// MFMA 16x16x32 bf16. Block = 256 thr = 4 waves x 16 rows = 64 rows, all 128 co.
// Fused BN partials -> one atomicAdd per channel per block.
__global__ __launch_bounds__(256) void sage_gemm(
    const ushort16* __restrict__ xb, const ushort16* __restrict__ mean_b,
    const ushort16* __restrict__ wct, const float* __restrict__ bl,
    float* __restrict__ h, float* __restrict__ bn, int nNodes)
{
    __shared__ float redS[4][CH];
    __shared__ float redQ[4][CH];

    int tid = threadIdx.x;
    int wave = tid >> 6, lane = tid & 63;
    int col = lane & 15, kg = lane >> 4;
    int rowBase = blockIdx.x * 64 + wave * 16;

    int arow = min(rowBase + col, nNodes - 1);          // A-frag row = lane&15
    const ushort16* xrow = xb + (size_t)arow * CH;
    const ushort16* mrow = mean_b + (size_t)arow * CH;

    f32x4 acc[8];
    #pragma unroll
    for (int cb = 0; cb < 8; ++cb) acc[cb] = (f32x4){0.f, 0.f, 0.f, 0.f};

    #pragma unroll
    for (int kstep = 0; kstep < 8; ++kstep) {
        const ushort16* asrc = (kstep < 4) ? (xrow + kstep * 32 + kg * 8)
                                           : (mrow + (kstep - 4) * 32 + kg * 8);
        bf16x8 a = *(const bf16x8*)asrc;
        #pragma unroll
        for (int cb = 0; cb < 8; ++cb) {
            const ushort16* bsrc = wct + (size_t)(cb * 16 + col) * 256 + kstep * 32 + kg * 8;
            bf16x8 b = *(const bf16x8*)bsrc;
            acc[cb] = __builtin_amdgcn_mfma_f32_16x16x32_bf16(a, b, acc[cb], 0, 0, 0);
        }
    }

    // epilogue: bias, store h, BN partial sums
    #pragma unroll
    for (int cb = 0; cb < 8; ++cb) {
        int co = cb * 16 + col;
        float blv = bl[co];
        float s = 0.f, ss = 0.f;
        #pragma unroll
        for (int j = 0; j < 4; ++j) {
            int r = rowBase + kg * 4 + j;               // C row = (lane>>4)*4+j
            float v = acc[cb][j] + blv;
            if (r < nNodes) {
                h[(size_t)r * CH + co] = v;
                s += v;
                ss += v * v;
            }
        }
        s  += __shfl_xor(s, 16);  s  += __shfl_xor(s, 32);
        ss += __shfl_xor(ss, 16); ss += __shfl_xor(ss, 32);
        if (kg == 0) { redS[wave][co] = s; redQ[wave][co] = ss; }
    }
    __syncthreads();
    if (tid < CH) {
        atomicAdd(&bn[tid], redS[0][tid] + redS[1][tid] + redS[2][tid] + redS[3][tid]);
    } else {
        int c = tid - CH;
        atomicAdd(&bn[CH + c], redQ[0][c] + redQ[1][c] + redQ[2][c] + redQ[3][c]);
    }
}

// ---------------------------------------------------------------------------
// Fused BN-finalize + apply: every block recomputes scale/shift from bn sums
// (128-wide, ~1us of redundant VALU), then normalizes+ReLUs its h slice.
__global__ __launch_bounds__(256) void sage_apply(
    float* __restrict__ h, const float* __restrict__ bn,
    const float* __restrict__ gamma, const float* __restrict__ beta,
    int total4, int nNodes)
{
    __shared__ float sc_sh[CH], sh_sh[CH];
    int tid = threadIdx.x;
    if (tid < CH) {
        float invN = 1.0f / (float)nNodes;
        float mu = bn[tid] * invN;
        float var = fmaxf(bn[CH + tid] * invN - mu * mu, 0.f);
        float sc = gamma[tid] * rsqrtf(var + BN_EPS);
        sc_sh[tid] = sc;
        sh_sh[tid] = beta[tid] - mu * sc;
    }
    __syncthreads();
    int i = blockIdx.x * 256 + tid;
    if (i >= total4) return;
    float4 v = reinterpret_cast<float4*>(h)[i];
    int c = (i * 4) & 127;
    float4 sc = *reinterpret_cast<const float4*>(&sc_sh[c]);
    float4 sh = *reinterpret_cast<const float4*>(&sh_sh[c]);
    v.x = fmaxf(fmaf(v.x, sc.x, sh.x), 0.f);
    v.y = fmaxf(fmaf(v.y, sc.y, sh.y), 0.f);
    v.z = fmaxf(fmaf(v.z, sc.z, sh.z), 0.f);
    v.w = fmaxf(fmaf(v.w, sc.w, sh.w), 0.f);
    reinterpret_cast<float4*>(h)[i] = v;
}

// ---------------------------------------------------------------------------
extern "C" void kernel_launch(void* const* d_in, const int* in_sizes, int n_in,
                              void* d_out, int out_size, void* d_ws, size_t ws_size,
                              hipStream_t stream)
{
    const float* x     = (const float*)d_in[0];
    const void*  ei    = d_in[1];
    const float* Wl    = (const float*)d_in[2];
    const float* bl    = (const float*)d_in[3];
    const float* Wr    = (const float*)d_in[4];
    const float* gamma = (const float*)d_in[5];
    const float* beta  = (const float*)d_in[6];

    int nNodes = in_sizes[0] / CH;
    int nEdges = in_sizes[1] / 2;
    int nBlkM  = (nNodes + 63) / 64;

    // ws layout (256B-aligned slabs)
    char* p = (char*)d_ws;
    auto take = [&](size_t bytes) {
        char* r = p;
        p += (bytes + 255) & ~(size_t)255;
        return r;
    };
    ushort16* xb      = (ushort16*)take((size_t)nNodes * CH * 2);      // 12.8 MB
    char*     xq      = (char*)take((size_t)nNodes * CH + 128);       // 6.4 MB fp8 + zero row
    ushort16* mean_b  = (ushort16*)take((size_t)nNodes * CH * 2);      // 12.8 MB
    ushort16* wct     = (ushort16*)take((size_t)CH * 256 * 2);         // 64 KB
    int*      head    = (int*)take((size_t)nNodes * 4);                // memset 0xFF
    float*    bn      = (float*)take(256 * 4);                         // zeroed in prep
    int2*     pair    = (int2*)take((size_t)nEdges * 8);               // 6.4 MB

    float* h = (float*)d_out;

    hipMemsetAsync(head, 0xFF, (size_t)nNodes * 4, stream);            // head = -1

    int total8 = nNodes * CH / 8;
    int eBlocks = (nEdges + 255) / 256;
    int pBlocks = max(eBlocks, (total8 + 255) / 256);
    sage_prep<<<pBlocks, 256, 0, stream>>>(
        x, ei, Wl, Wr, head, pair, (uint32*)xb, (uint2*)xq, wct, bn,
        nEdges, total8);

    int aBlocks = (nNodes + 15) / 16;   // 4 nodes/wave, 4 waves/block
    sage_aggregate<<<aBlocks, 256, 0, stream>>>(
        xq, head, pair, (uint32*)mean_b, nNodes);

    sage_gemm<<<nBlkM, 256, 0, stream>>>(
        xb, mean_b, wct, bl, h, bn, nNodes);

    int total4 = nNodes * CH / 4;
    sage_apply<<<(total4 + 255) / 256, 256, 0, stream>>>(
        h, bn, gamma, beta, total4, nNodes);
}

// Round 9
// 134.219 us; speedup vs baseline: 1.4559x; 1.1218x over previous
//
#include <hip/hip_runtime.h>

#define CH 128
#define BN_EPS 1e-5f

typedef unsigned int uint32;
typedef unsigned short ushort16;
using f32x4  = __attribute__((ext_vector_type(4))) float;
using bf16x8 = __attribute__((ext_vector_type(8))) short;

__device__ __forceinline__ ushort16 f2b(float f) {
    uint32 u = __float_as_uint(f);
    return (ushort16)((u + 0x7FFFu + ((u >> 16) & 1u)) >> 16);   // RNE
}

// ---------------------------------------------------------------------------
// Fused prep kernel (grid = 3125 blocks x 256):
//  (a) edge-chain build: head[d] <- atomicExch, pair[e] = {next, src}
//      (int64-vs-int32 detect inline via ballot over first 64 odd words)
//  (b) x f32 -> xb bf16 (GEMM operand) AND xq fp8-e4m3 (gather operand)
//  (c) blocks [0,128): WcT[co][k] bf16 build (k<128 -> Wr, k>=128 -> Wl)
//  (d) block 0: zero bn[0:256]; block 1: zero the fp8 zero-row (index nNodes)
__global__ __launch_bounds__(256) void sage_prep(
    const float* __restrict__ x, const void* __restrict__ ei,
    const float* __restrict__ Wl, const float* __restrict__ Wr,
    int* __restrict__ head, int2* __restrict__ pair,
    uint32* __restrict__ xb4, uint2* __restrict__ xq8,
    ushort16* __restrict__ wct, float* __restrict__ bn,
    int nEdges, int total8)
{
    const int* pi = (const int*)ei;
    int lane = threadIdx.x & 63;
    int probe = pi[lane * 2 + 1];
    bool is64 = (__ballot(probe != 0) == 0ULL);

    int e = blockIdx.x * 256 + threadIdx.x;
    if (e < nEdges) {
        int s, d;
        if (is64) {
            const long long* p = (const long long*)ei;
            s = (int)p[e];
            d = (int)p[nEdges + e];
        } else {
            s = pi[e];
            d = pi[nEdges + e];
        }
        int old = atomicExch(&head[d], e);
        pair[e] = make_int2(old, s);
    }

    int i = blockIdx.x * 256 + threadIdx.x;
    if (i < total8) {
        const float4* x4 = (const float4*)x;
        float4 a = x4[2 * i], b = x4[2 * i + 1];
        uint4 o;
        o.x = (uint32)f2b(a.x) | ((uint32)f2b(a.y) << 16);
        o.y = (uint32)f2b(a.z) | ((uint32)f2b(a.w) << 16);
        o.z = (uint32)f2b(b.x) | ((uint32)f2b(b.y) << 16);
        o.w = (uint32)f2b(b.z) | ((uint32)f2b(b.w) << 16);
        ((uint4*)xb4)[i] = o;

        int qa = __builtin_amdgcn_cvt_pk_fp8_f32(a.x, a.y, 0, false);
        qa = __builtin_amdgcn_cvt_pk_fp8_f32(a.z, a.w, qa, true);
        int qb = __builtin_amdgcn_cvt_pk_fp8_f32(b.x, b.y, 0, false);
        qb = __builtin_amdgcn_cvt_pk_fp8_f32(b.z, b.w, qb, true);
        xq8[i] = make_uint2((uint32)qa, (uint32)qb);
    }

    if (blockIdx.x < 128) {
        int idx = blockIdx.x * 256 + threadIdx.x;    // covers 128*256 = CH*256
        int co = idx >> 8, k = idx & 255;
        float v = (k < 128) ? Wr[co * 128 + k] : Wl[co * 128 + (k - 128)];
        wct[idx] = f2b(v);
    }
    if (blockIdx.x == 0) bn[threadIdx.x] = 0.f;      // bn_sum[128] + bn_sumsq[128]
    if (blockIdx.x == 1 && threadIdx.x < 32)         // fp8 zero-row at index nNodes
        ((uint32*)(xq8))[(size_t)total8 * 2 + threadIdx.x] = 0;
}

// ---------------------------------------------------------------------------
// Chain-walk gather, instruction-economized (R8 structure, unchanged):
// 3 VMEM instrs per 4 edges; fp8 rows; walker state in lanes 0-3.
__global__ __launch_bounds__(256) void sage_aggregate(
    const char* __restrict__ xq, const int* __restrict__ head,
    const int2* __restrict__ pair, uint32* __restrict__ mean_b, int nNodes)
{
    int wid = blockIdx.x * 4 + (threadIdx.x >> 6);
    int nbase = wid * 4;
    if (nbase >= nNodes) return;
    int lane = threadIdx.x & 63;
    int half = lane >> 5;            // 0: chains 0/2, 1: chains 1/3
    int sub = lane & 31;

    const int ZROW = nNodes;         // zeroed fp8 row

    int cur = -1;
    if (lane < 4) {
        int n = nbase + lane;
        cur = (n < nNodes) ? head[n] : -1;
    }
    int cnt = 0;
    float4 accA = {0.f, 0.f, 0.f, 0.f};   // chain (half)   : 0 or 1
    float4 accB = {0.f, 0.f, 0.f, 0.f};   // chain (2+half) : 2 or 3

    while (__ballot(cur >= 0) != 0ULL) {
        int2 pr = make_int2(-1, ZROW);
        if (cur >= 0) pr = pair[cur];                 // 1 VMEM for 4 chains
        int s0 = __shfl(pr.y, 0), s1 = __shfl(pr.y, 1);
        int s2 = __shfl(pr.y, 2), s3 = __shfl(pr.y, 3);

        int sA = half ? s1 : s0;
        int sB = half ? s3 : s2;
        uint32 uA = *(const uint32*)(xq + ((size_t)sA << 7) + sub * 4);
        uint32 uB = *(const uint32*)(xq + ((size_t)sB << 7) + sub * 4);

        accA.x += __builtin_amdgcn_cvt_f32_fp8(uA, 0);
        accA.y += __builtin_amdgcn_cvt_f32_fp8(uA, 1);
        accA.z += __builtin_amdgcn_cvt_f32_fp8(uA, 2);
        accA.w += __builtin_amdgcn_cvt_f32_fp8(uA, 3);
        accB.x += __builtin_amdgcn_cvt_f32_fp8(uB, 0);
        accB.y += __builtin_amdgcn_cvt_f32_fp8(uB, 1);
        accB.z += __builtin_amdgcn_cvt_f32_fp8(uB, 2);
        accB.w += __builtin_amdgcn_cvt_f32_fp8(uB, 3);

        if (cur >= 0) { ++cnt; cur = pr.x; }
    }

    int cA = __shfl(cnt, half);
    int cB = __shfl(cnt, 2 + half);
    float invA = 1.0f / fmaxf((float)cA, 1.0f);
    float invB = 1.0f / fmaxf((float)cB, 1.0f);

    int nA = nbase + half;
    if (nA < nNodes) {
        uint2 o;
        o.x = (uint32)f2b(accA.x * invA) | ((uint32)f2b(accA.y * invA) << 16);
        o.y = (uint32)f2b(accA.z * invA) | ((uint32)f2b(accA.w * invA) << 16);
        *(uint2*)((char*)mean_b + (size_t)nA * 256 + sub * 8) = o;
    }
    int nB = nbase + 2 + half;
    if (nB < nNodes) {
        uint2 o;
        o.x = (uint32)f2b(accB.x * invB) | ((uint32)f2b(accB.y * invB) << 16);
        o.y = (uint32)f2b(accB.z * invB) | ((uint32)f2b(accB.w * invB) << 16);
        *(uint2*)((char*)mean_b + (size_t)nB * 256 + sub * 8) = o;
    }
}

// ---------------------------------------------------------------------------
// h[n][co] = sum_k Xc[n][k] * WcT[co][k] + bl[co], Xc = [xb | mean_b] (K=256).
// R9 change: wct staged into LDS in MFMA-FRAGMENT ORDER:
//   wsh[(cb*8+kstep)*64 + lane] = the 16B B-frag lane needs.
// Inner loop B-reads become ds_read_b128 at lane*16 (canonical conflict-free
// stride-1 pattern) instead of 64 serialized ~200cy L2 loads with only 52
// VGPRs of pipelining room. A-frags hoisted to registers before the K-loop.
__global__ __launch_bounds__(256) void sage_gemm(
    const ushort16* __restrict__ xb, const ushort16* __restrict__ mean_b,
    const ushort16* __restrict__ wct, const float* __restrict__ bl,
    float* __restrict__ h, float* __restrict__ bn, int nNodes)
{
    __shared__ ushort16 wsh[8 * 8 * 64 * 8];   // 64 KB, fragment-ordered
    __shared__ float redS[4][CH];
    __shared__ float redQ[4][CH];

    int tid = threadIdx.x;
    int wave = tid >> 6, lane = tid & 63;
    int col = lane & 15, kg = lane >> 4;

    // stage B: each wave stages 16 (cb,kstep) pairs; one-time per block
    #pragma unroll
    for (int it = 0; it < 16; ++it) {
        int pidx = wave * 16 + it;               // pidx = cb*8 + kstep
        int cb = pidx >> 3, ks = pidx & 7;
        bf16x8 v = *(const bf16x8*)(wct + (size_t)(cb * 16 + col) * 256 + ks * 32 + kg * 8);
        *(bf16x8*)(wsh + ((size_t)pidx * 64 + lane) * 8) = v;
    }

    int rowBase = blockIdx.x * 64 + wave * 16;
    int arow = min(rowBase + col, nNodes - 1);          // A-frag row = lane&15
    const ushort16* xrow = xb + (size_t)arow * CH;
    const ushort16* mrow = mean_b + (size_t)arow * CH;

    // hoist A-frags (8 x 16B per lane, pipelined global loads)
    bf16x8 afrag[8];
    #pragma unroll
    for (int t = 0; t < 4; ++t)
        afrag[t] = *(const bf16x8*)(xrow + t * 32 + kg * 8);
    #pragma unroll
    for (int t = 0; t < 4; ++t)
        afrag[4 + t] = *(const bf16x8*)(mrow + t * 32 + kg * 8);

    __syncthreads();

    f32x4 acc[8];
    #pragma unroll
    for (int cb = 0; cb < 8; ++cb) acc[cb] = (f32x4){0.f, 0.f, 0.f, 0.f};

    #pragma unroll
    for (int kstep = 0; kstep < 8; ++kstep) {
        bf16x8 a = afrag[kstep];
        #pragma unroll
        for (int cb = 0; cb < 8; ++cb) {
            bf16x8 b = *(const bf16x8*)(wsh + ((size_t)(cb * 8 + kstep) * 64 + lane) * 8);
            acc[cb] = __builtin_amdgcn_mfma_f32_16x16x32_bf16(a, b, acc[cb], 0, 0, 0);
        }
    }

    // epilogue: bias, store h, BN partial sums
    #pragma unroll
    for (int cb = 0; cb < 8; ++cb) {
        int co = cb * 16 + col;
        float blv = bl[co];
        float s = 0.f, ss = 0.f;
        #pragma unroll
        for (int j = 0; j < 4; ++j) {
            int r = rowBase + kg * 4 + j;               // C row = (lane>>4)*4+j
            float v = acc[cb][j] + blv;
            if (r < nNodes) {
                h[(size_t)r * CH + co] = v;
                s += v;
                ss += v * v;
            }
        }
        s  += __shfl_xor(s, 16);  s  += __shfl_xor(s, 32);
        ss += __shfl_xor(ss, 16); ss += __shfl_xor(ss, 32);
        if (kg == 0) { redS[wave][co] = s; redQ[wave][co] = ss; }
    }
    __syncthreads();
    if (tid < CH) {
        atomicAdd(&bn[tid], redS[0][tid] + redS[1][tid] + redS[2][tid] + redS[3][tid]);
    } else {
        int c = tid - CH;
        atomicAdd(&bn[CH + c], redQ[0][c] + redQ[1][c] + redQ[2][c] + redQ[3][c]);
    }
}

// ---------------------------------------------------------------------------
// Fused BN-finalize + apply: every block recomputes scale/shift from bn sums
// (128-wide, ~1us of redundant VALU), then normalizes+ReLUs its h slice.
__global__ __launch_bounds__(256) void sage_apply(
    float* __restrict__ h, const float* __restrict__ bn,
    const float* __restrict__ gamma, const float* __restrict__ beta,
    int total4, int nNodes)
{
    __shared__ float sc_sh[CH], sh_sh[CH];
    int tid = threadIdx.x;
    if (tid < CH) {
        float invN = 1.0f / (float)nNodes;
        float mu = bn[tid] * invN;
        float var = fmaxf(bn[CH + tid] * invN - mu * mu, 0.f);
        float sc = gamma[tid] * rsqrtf(var + BN_EPS);
        sc_sh[tid] = sc;
        sh_sh[tid] = beta[tid] - mu * sc;
    }
    __syncthreads();
    int i = blockIdx.x * 256 + tid;
    if (i >= total4) return;
    float4 v = reinterpret_cast<float4*>(h)[i];
    int c = (i * 4) & 127;
    float4 sc = *reinterpret_cast<const float4*>(&sc_sh[c]);
    float4 sh = *reinterpret_cast<const float4*>(&sh_sh[c]);
    v.x = fmaxf(fmaf(v.x, sc.x, sh.x), 0.f);
    v.y = fmaxf(fmaf(v.y, sc.y, sh.y), 0.f);
    v.z = fmaxf(fmaf(v.z, sc.z, sh.z), 0.f);
    v.w = fmaxf(fmaf(v.w, sc.w, sh.w), 0.f);
    reinterpret_cast<float4*>(h)[i] = v;
}

// ---------------------------------------------------------------------------
extern "C" void kernel_launch(void* const* d_in, const int* in_sizes, int n_in,
                              void* d_out, int out_size, void* d_ws, size_t ws_size,
                              hipStream_t stream)
{
    const float* x     = (const float*)d_in[0];
    const void*  ei    = d_in[1];
    const float* Wl    = (const float*)d_in[2];
    const float* bl    = (const float*)d_in[3];
    const float* Wr    = (const float*)d_in[4];
    const float* gamma = (const float*)d_in[5];
    const float* beta  = (const float*)d_in[6];

    int nNodes = in_sizes[0] / CH;
    int nEdges = in_sizes[1] / 2;
    int nBlkM  = (nNodes + 63) / 64;

    // ws layout (256B-aligned slabs)
    char* p = (char*)d_ws;
    auto take = [&](size_t bytes) {
        char* r = p;
        p += (bytes + 255) & ~(size_t)255;
        return r;
    };
    ushort16* xb      = (ushort16*)take((size_t)nNodes * CH * 2);      // 12.8 MB
    char*     xq      = (char*)take((size_t)nNodes * CH + 128);       // 6.4 MB fp8 + zero row
    ushort16* mean_b  = (ushort16*)take((size_t)nNodes * CH * 2);      // 12.8 MB
    ushort16* wct     = (ushort16*)take((size_t)CH * 256 * 2);         // 64 KB
    int*      head    = (int*)take((size_t)nNodes * 4);                // memset 0xFF
    float*    bn      = (float*)take(256 * 4);                         // zeroed in prep
    int2*     pair    = (int2*)take((size_t)nEdges * 8);               // 6.4 MB

    float* h = (float*)d_out;

    hipMemsetAsync(head, 0xFF, (size_t)nNodes * 4, stream);            // head = -1

    int total8 = nNodes * CH / 8;
    int eBlocks = (nEdges + 255) / 256;
    int pBlocks = max(eBlocks, (total8 + 255) / 256);
    sage_prep<<<pBlocks, 256, 0, stream>>>(
        x, ei, Wl, Wr, head, pair, (uint32*)xb, (uint2*)xq, wct, bn,
        nEdges, total8);

    int aBlocks = (nNodes + 15) / 16;   // 4 nodes/wave, 4 waves/block
    sage_aggregate<<<aBlocks, 256, 0, stream>>>(
        xq, head, pair, (uint32*)mean_b, nNodes);

    sage_gemm<<<nBlkM, 256, 0, stream>>>(
        xb, mean_b, wct, bl, h, bn, nNodes);

    int total4 = nNodes * CH / 4;
    sage_apply<<<(total4 + 255) / 256, 256, 0, stream>>>(
        h, bn, gamma, beta, total4, nNodes);
}

// Round 10
// 125.307 us; speedup vs baseline: 1.5595x; 1.0711x over previous
//
#include <hip/hip_runtime.h>

#define CH 128
#define BN_EPS 1e-5f

typedef unsigned int uint32;
typedef unsigned short ushort16;
using f32x4  = __attribute__((ext_vector_type(4))) float;
using bf16x8 = __attribute__((ext_vector_type(8))) short;

__device__ __forceinline__ ushort16 f2b(float f) {
    uint32 u = __float_as_uint(f);
    return (ushort16)((u + 0x7FFFu + ((u >> 16) & 1u)) >> 16);   // RNE
}
__device__ __forceinline__ uint32 pk2(float a, float b) {
    return (uint32)f2b(a) | ((uint32)f2b(b) << 16);
}

// ---------------------------------------------------------------------------
// Fused prep kernel (grid = 1563 blocks x 256), 2 edges + 2 chunks per thread
// for doubled memory ILP (prep was latency-chain bound, not BW bound):
//  (a) edge-chain build: head[d] <- atomicExch, pair[e] = {next, src};
//      paired 16B ei loads, one int4 store for both pairs.
//  (b) x f32 -> xb bf16 AND xq fp8-e4m3, 16 elems/thread.
//  (c) blocks [0,128): WcT[co][k] bf16 (k<128 -> Wr, k>=128 -> Wl)
//  (d) block 0: zero bn[0:256]; block 1: zero fp8 zero-row (index nNodes)
__global__ __launch_bounds__(256) void sage_prep(
    const float* __restrict__ x, const void* __restrict__ ei,
    const float* __restrict__ Wl, const float* __restrict__ Wr,
    int* __restrict__ head, int2* __restrict__ pair,
    uint32* __restrict__ xb4, uint2* __restrict__ xq8,
    ushort16* __restrict__ wct, float* __restrict__ bn,
    int nEdges, int total8)
{
    const int* pi = (const int*)ei;
    int lane = threadIdx.x & 63;
    int probe = pi[lane * 2 + 1];
    bool is64 = (__ballot(probe != 0) == 0ULL);

    int idx = blockIdx.x * 256 + threadIdx.x;
    int e0 = idx * 2, e1 = e0 + 1;
    if (e0 < nEdges) {
        bool has1 = (e1 < nEdges);
        int s0, d0, s1 = 0, d1 = 0;
        if (is64) {
            const long long* p = (const long long*)ei;
            long long a0 = p[e0];
            long long a1 = has1 ? p[e1] : 0;
            long long b0 = p[nEdges + e0];
            long long b1 = has1 ? p[nEdges + e1] : 0;
            s0 = (int)a0; s1 = (int)a1; d0 = (int)b0; d1 = (int)b1;
        } else {
            s0 = pi[e0]; s1 = has1 ? pi[e1] : 0;
            d0 = pi[nEdges + e0]; d1 = has1 ? pi[nEdges + e1] : 0;
        }
        int old0 = atomicExch(&head[d0], e0);
        int old1 = has1 ? atomicExch(&head[d1], e1) : 0;
        if (has1) {
            int4 pk = make_int4(old0, s0, old1, s1);
            *(int4*)(pair + e0) = pk;
        } else {
            pair[e0] = make_int2(old0, s0);
        }
    }

    int i0 = idx * 2, i1 = i0 + 1;
    if (i0 < total8) {
        const float4* x4 = (const float4*)x;
        float4 a = x4[2 * i0], b = x4[2 * i0 + 1];
        bool has1 = (i1 < total8);
        float4 c = has1 ? x4[2 * i1] : make_float4(0, 0, 0, 0);
        float4 d = has1 ? x4[2 * i1 + 1] : make_float4(0, 0, 0, 0);

        uint4 o0 = make_uint4(pk2(a.x, a.y), pk2(a.z, a.w), pk2(b.x, b.y), pk2(b.z, b.w));
        ((uint4*)xb4)[i0] = o0;
        if (has1) {
            uint4 o1 = make_uint4(pk2(c.x, c.y), pk2(c.z, c.w), pk2(d.x, d.y), pk2(d.z, d.w));
            ((uint4*)xb4)[i1] = o1;
        }

        int qa = __builtin_amdgcn_cvt_pk_fp8_f32(a.x, a.y, 0, false);
        qa = __builtin_amdgcn_cvt_pk_fp8_f32(a.z, a.w, qa, true);
        int qb = __builtin_amdgcn_cvt_pk_fp8_f32(b.x, b.y, 0, false);
        qb = __builtin_amdgcn_cvt_pk_fp8_f32(b.z, b.w, qb, true);
        if (has1) {
            int qc = __builtin_amdgcn_cvt_pk_fp8_f32(c.x, c.y, 0, false);
            qc = __builtin_amdgcn_cvt_pk_fp8_f32(c.z, c.w, qc, true);
            int qd = __builtin_amdgcn_cvt_pk_fp8_f32(d.x, d.y, 0, false);
            qd = __builtin_amdgcn_cvt_pk_fp8_f32(d.z, d.w, qd, true);
            *(uint4*)(xq8 + i0) = make_uint4((uint32)qa, (uint32)qb, (uint32)qc, (uint32)qd);
        } else {
            xq8[i0] = make_uint2((uint32)qa, (uint32)qb);
        }
    }

    if (blockIdx.x < 128) {
        int widx = blockIdx.x * 256 + threadIdx.x;   // covers 128*256 = CH*256
        int co = widx >> 8, k = widx & 255;
        float v = (k < 128) ? Wr[co * 128 + k] : Wl[co * 128 + (k - 128)];
        wct[widx] = f2b(v);
    }
    if (blockIdx.x == 0) bn[threadIdx.x] = 0.f;      // bn_sum[128] + bn_sumsq[128]
    if (blockIdx.x == 1 && threadIdx.x < 32)         // fp8 zero-row at index nNodes
        ((uint32*)(xq8))[(size_t)total8 * 2 + threadIdx.x] = 0;
}

// ---------------------------------------------------------------------------
// Chain-walk gather, 8 chains per wave, 2 VMEM wave-instrs per step (8 edges):
//  - walker state (cur,cnt) in lanes 0-7; one masked 8B pair[] gather.
//  - ONE dwordx4 row load: lane l reads 16B of chain (l>>3)'s fp8 row at
//    slot (l&7); 8 lanes x 16B = 128B row, 8 rows per instruction.
//  - chain->lane row broadcast via single variable-lane shfl (ds_bpermute).
//  - finished chains redirect to zeroed row at index nNodes (branchless).
// Lane covers channels 16*(l&7) .. +15; per-lane acc[16] f32.
__global__ __launch_bounds__(256) void sage_aggregate(
    const char* __restrict__ xq, const int* __restrict__ head,
    const int2* __restrict__ pair, uint32* __restrict__ mean_b, int nNodes)
{
    int wid = blockIdx.x * 4 + (threadIdx.x >> 6);
    int nbase = wid * 8;
    if (nbase >= nNodes) return;
    int lane = threadIdx.x & 63;
    int chain = lane >> 3;           // 0..7
    int sub = lane & 7;              // 16B slot within the 128B row

    const int ZROW = nNodes;         // zeroed fp8 row

    int cur = -1;
    if (lane < 8) {
        int n = nbase + lane;
        cur = (n < nNodes) ? head[n] : -1;
    }
    int cnt = 0;
    float acc[16];
    #pragma unroll
    for (int i = 0; i < 16; ++i) acc[i] = 0.f;

    while (__ballot(cur >= 0) != 0ULL) {
        int2 pr = make_int2(-1, ZROW);
        if (cur >= 0) pr = pair[cur];                 // 1 VMEM for 8 chains
        int s = __shfl(pr.y, chain);                  // my chain's src row
        uint4 u = *(const uint4*)(xq + ((size_t)s << 7) + sub * 16);
        #pragma unroll
        for (int w = 0; w < 4; ++w) {
            uint32 uw = (&u.x)[w];
            acc[w * 4 + 0] += __builtin_amdgcn_cvt_f32_fp8(uw, 0);
            acc[w * 4 + 1] += __builtin_amdgcn_cvt_f32_fp8(uw, 1);
            acc[w * 4 + 2] += __builtin_amdgcn_cvt_f32_fp8(uw, 2);
            acc[w * 4 + 3] += __builtin_amdgcn_cvt_f32_fp8(uw, 3);
        }
        if (cur >= 0) { ++cnt; cur = pr.x; }
    }

    int cn = __shfl(cnt, chain);
    float inv = 1.0f / fmaxf((float)cn, 1.0f);
    int n = nbase + chain;
    if (n < nNodes) {
        // 16 channels -> 32B bf16 at row n*256, offset sub*32
        uint4 o0 = make_uint4(pk2(acc[0] * inv, acc[1] * inv),
                              pk2(acc[2] * inv, acc[3] * inv),
                              pk2(acc[4] * inv, acc[5] * inv),
                              pk2(acc[6] * inv, acc[7] * inv));
        uint4 o1 = make_uint4(pk2(acc[8] * inv, acc[9] * inv),
                              pk2(acc[10] * inv, acc[11] * inv),
                              pk2(acc[12] * inv, acc[13] * inv),
                              pk2(acc[14] * inv, acc[15] * inv));
        char* base = (char*)mean_b + (size_t)n * 256 + sub * 32;
        *(uint4*)base = o0;
        *(uint4*)(base + 16) = o1;
    }
}

// ---------------------------------------------------------------------------
// h[n][co] = sum_k Xc[n][k] * WcT[co][k] + bl[co], Xc = [xb | mean_b] (K=256).
// wct staged into LDS in MFMA-fragment order; ds_read_b128 inner loop;
// A-frags hoisted. Fused BN partials -> one atomicAdd per channel per block.
__global__ __launch_bounds__(256) void sage_gemm(
    const ushort16* __restrict__ xb, const ushort16* __restrict__ mean_b,
    const ushort16* __restrict__ wct, const float* __restrict__ bl,
    float* __restrict__ h, float* __restrict__ bn, int nNodes)
{
    __shared__ ushort16 wsh[8 * 8 * 64 * 8];   // 64 KB, fragment-ordered
    __shared__ float redS[4][CH];
    __shared__ float redQ[4][CH];

    int tid = threadIdx.x;
    int wave = tid >> 6, lane = tid & 63;
    int col = lane & 15, kg = lane >> 4;

    #pragma unroll
    for (int it = 0; it < 16; ++it) {
        int pidx = wave * 16 + it;               // pidx = cb*8 + kstep
        int cb = pidx >> 3, ks = pidx & 7;
        bf16x8 v = *(const bf16x8*)(wct + (size_t)(cb * 16 + col) * 256 + ks * 32 + kg * 8);
        *(bf16x8*)(wsh + ((size_t)pidx * 64 + lane) * 8) = v;
    }

    int rowBase = blockIdx.x * 64 + wave * 16;
    int arow = min(rowBase + col, nNodes - 1);          // A-frag row = lane&15
    const ushort16* xrow = xb + (size_t)arow * CH;
    const ushort16* mrow = mean_b + (size_t)arow * CH;

    bf16x8 afrag[8];
    #pragma unroll
    for (int t = 0; t < 4; ++t)
        afrag[t] = *(const bf16x8*)(xrow + t * 32 + kg * 8);
    #pragma unroll
    for (int t = 0; t < 4; ++t)
        afrag[4 + t] = *(const bf16x8*)(mrow + t * 32 + kg * 8);

    __syncthreads();

    f32x4 acc[8];
    #pragma unroll
    for (int cb = 0; cb < 8; ++cb) acc[cb] = (f32x4){0.f, 0.f, 0.f, 0.f};

    #pragma unroll
    for (int kstep = 0; kstep < 8; ++kstep) {
        bf16x8 a = afrag[kstep];
        #pragma unroll
        for (int cb = 0; cb < 8; ++cb) {
            bf16x8 b = *(const bf16x8*)(wsh + ((size_t)(cb * 8 + kstep) * 64 + lane) * 8);
            acc[cb] = __builtin_amdgcn_mfma_f32_16x16x32_bf16(a, b, acc[cb], 0, 0, 0);
        }
    }

    #pragma unroll
    for (int cb = 0; cb < 8; ++cb) {
        int co = cb * 16 + col;
        float blv = bl[co];
        float s = 0.f, ss = 0.f;
        #pragma unroll
        for (int j = 0; j < 4; ++j) {
            int r = rowBase + kg * 4 + j;               // C row = (lane>>4)*4+j
            float v = acc[cb][j] + blv;
            if (r < nNodes) {
                h[(size_t)r * CH + co] = v;
                s += v;
                ss += v * v;
            }
        }
        s  += __shfl_xor(s, 16);  s  += __shfl_xor(s, 32);
        ss += __shfl_xor(ss, 16); ss += __shfl_xor(ss, 32);
        if (kg == 0) { redS[wave][co] = s; redQ[wave][co] = ss; }
    }
    __syncthreads();
    if (tid < CH) {
        atomicAdd(&bn[tid], redS[0][tid] + redS[1][tid] + redS[2][tid] + redS[3][tid]);
    } else {
        int c = tid - CH;
        atomicAdd(&bn[CH + c], redQ[0][c] + redQ[1][c] + redQ[2][c] + redQ[3][c]);
    }
}

// ---------------------------------------------------------------------------
// Fused BN-finalize + apply.
__global__ __launch_bounds__(256) void sage_apply(
    float* __restrict__ h, const float* __restrict__ bn,
    const float* __restrict__ gamma, const float* __restrict__ beta,
    int total4, int nNodes)
{
    __shared__ float sc_sh[CH], sh_sh[CH];
    int tid = threadIdx.x;
    if (tid < CH) {
        float invN = 1.0f / (float)nNodes;
        float mu = bn[tid] * invN;
        float var = fmaxf(bn[CH + tid] * invN - mu * mu, 0.f);
        float sc = gamma[tid] * rsqrtf(var + BN_EPS);
        sc_sh[tid] = sc;
        sh_sh[tid] = beta[tid] - mu * sc;
    }
    __syncthreads();
    int i = blockIdx.x * 256 + tid;
    if (i >= total4) return;
    float4 v = reinterpret_cast<float4*>(h)[i];
    int c = (i * 4) & 127;
    float4 sc = *reinterpret_cast<const float4*>(&sc_sh[c]);
    float4 sh = *reinterpret_cast<const float4*>(&sh_sh[c]);
    v.x = fmaxf(fmaf(v.x, sc.x, sh.x), 0.f);
    v.y = fmaxf(fmaf(v.y, sc.y, sh.y), 0.f);
    v.z = fmaxf(fmaf(v.z, sc.z, sh.z), 0.f);
    v.w = fmaxf(fmaf(v.w, sc.w, sh.w), 0.f);
    reinterpret_cast<float4*>(h)[i] = v;
}

// ---------------------------------------------------------------------------
extern "C" void kernel_launch(void* const* d_in, const int* in_sizes, int n_in,
                              void* d_out, int out_size, void* d_ws, size_t ws_size,
                              hipStream_t stream)
{
    const float* x     = (const float*)d_in[0];
    const void*  ei    = d_in[1];
    const float* Wl    = (const float*)d_in[2];
    const float* bl    = (const float*)d_in[3];
    const float* Wr    = (const float*)d_in[4];
    const float* gamma = (const float*)d_in[5];
    const float* beta  = (const float*)d_in[6];

    int nNodes = in_sizes[0] / CH;
    int nEdges = in_sizes[1] / 2;
    int nBlkM  = (nNodes + 63) / 64;

    // ws layout (256B-aligned slabs)
    char* p = (char*)d_ws;
    auto take = [&](size_t bytes) {
        char* r = p;
        p += (bytes + 255) & ~(size_t)255;
        return r;
    };
    ushort16* xb      = (ushort16*)take((size_t)nNodes * CH * 2);      // 12.8 MB
    char*     xq      = (char*)take((size_t)nNodes * CH + 128);       // 6.4 MB fp8 + zero row
    ushort16* mean_b  = (ushort16*)take((size_t)nNodes * CH * 2);      // 12.8 MB
    ushort16* wct     = (ushort16*)take((size_t)CH * 256 * 2);         // 64 KB
    int*      head    = (int*)take((size_t)nNodes * 4);                // memset 0xFF
    float*    bn      = (float*)take(256 * 4);                         // zeroed in prep
    int2*     pair    = (int2*)take((size_t)nEdges * 8);               // 6.4 MB

    float* h = (float*)d_out;

    hipMemsetAsync(head, 0xFF, (size_t)nNodes * 4, stream);            // head = -1

    int total8 = nNodes * CH / 8;
    int ePairs = (nEdges + 1) / 2;
    int cPairs = (total8 + 1) / 2;
    int pBlocks = (max(ePairs, cPairs) + 255) / 256;
    sage_prep<<<pBlocks, 256, 0, stream>>>(
        x, ei, Wl, Wr, head, pair, (uint32*)xb, (uint2*)xq, wct, bn,
        nEdges, total8);

    int aBlocks = (nNodes + 31) / 32;   // 8 nodes/wave, 4 waves/block
    sage_aggregate<<<aBlocks, 256, 0, stream>>>(
        xq, head, pair, (uint32*)mean_b, nNodes);

    sage_gemm<<<nBlkM, 256, 0, stream>>>(
        xb, mean_b, wct, bl, h, bn, nNodes);

    int total4 = nNodes * CH / 4;
    sage_apply<<<(total4 + 255) / 256, 256, 0, stream>>>(
        h, bn, gamma, beta, total4, nNodes);
}

// Round 11
// 124.585 us; speedup vs baseline: 1.5685x; 1.0058x over previous
//
#include <hip/hip_runtime.h>

#define CH 128
#define BN_EPS 1e-5f

typedef unsigned int uint32;
typedef unsigned short ushort16;
using f32x2  = __attribute__((ext_vector_type(2))) float;
using f32x4  = __attribute__((ext_vector_type(4))) float;
using bf16x8 = __attribute__((ext_vector_type(8))) short;

__device__ __forceinline__ ushort16 f2b(float f) {
    uint32 u = __float_as_uint(f);
    return (ushort16)((u + 0x7FFFu + ((u >> 16) & 1u)) >> 16);   // RNE
}
__device__ __forceinline__ uint32 pk2(float a, float b) {
    return (uint32)f2b(a) | ((uint32)f2b(b) << 16);
}
__device__ __forceinline__ float blo(uint32 u) { return __uint_as_float(u << 16); }
__device__ __forceinline__ float bhi(uint32 u) { return __uint_as_float(u & 0xFFFF0000u); }

// ---------------------------------------------------------------------------
// Fused prep kernel (grid = 3125 blocks x 256), 1 edge + 1 chunk per thread.
// x-loads hoisted ABOVE the edge/atomic chain so they fly during the
// atomicExch round-trip.
//  (a) edge-chain build: head[d] <- atomicExch, pair[e] = {next, src}
//  (b) x f32 -> xb bf16 AND xq fp8-e4m3 (8 elems/thread)
//  (c) blocks [0,128): WcT bf16 build   (d) block 0: bn=0; block 1: zero-row
__global__ __launch_bounds__(256) void sage_prep(
    const float* __restrict__ x, const void* __restrict__ ei,
    const float* __restrict__ Wl, const float* __restrict__ Wr,
    int* __restrict__ head, int2* __restrict__ pair,
    uint32* __restrict__ xb4, uint2* __restrict__ xq8,
    ushort16* __restrict__ wct, float* __restrict__ bn,
    int nEdges, int total8)
{
    const int* pi = (const int*)ei;
    int lane = threadIdx.x & 63;
    int probe = pi[lane * 2 + 1];
    bool is64 = (__ballot(probe != 0) == 0ULL);

    int idx = blockIdx.x * 256 + threadIdx.x;

    // hoisted convert-loads (issue before the atomic dependency chain)
    const float4* x4 = (const float4*)x;
    float4 a = make_float4(0, 0, 0, 0), b = make_float4(0, 0, 0, 0);
    bool hasC = (idx < total8);
    if (hasC) { a = x4[2 * idx]; b = x4[2 * idx + 1]; }

    if (idx < nEdges) {
        int s, d;
        if (is64) {
            const long long* p = (const long long*)ei;
            s = (int)p[idx];
            d = (int)p[nEdges + idx];
        } else {
            s = pi[idx];
            d = pi[nEdges + idx];
        }
        int old = atomicExch(&head[d], idx);
        pair[idx] = make_int2(old, s);
    }

    if (hasC) {
        uint4 o;
        o.x = pk2(a.x, a.y); o.y = pk2(a.z, a.w);
        o.z = pk2(b.x, b.y); o.w = pk2(b.z, b.w);
        ((uint4*)xb4)[idx] = o;

        int qa = __builtin_amdgcn_cvt_pk_fp8_f32(a.x, a.y, 0, false);
        qa = __builtin_amdgcn_cvt_pk_fp8_f32(a.z, a.w, qa, true);
        int qb = __builtin_amdgcn_cvt_pk_fp8_f32(b.x, b.y, 0, false);
        qb = __builtin_amdgcn_cvt_pk_fp8_f32(b.z, b.w, qb, true);
        xq8[idx] = make_uint2((uint32)qa, (uint32)qb);
    }

    if (blockIdx.x < 128) {
        int widx = blockIdx.x * 256 + threadIdx.x;   // covers 128*256 = CH*256
        int co = widx >> 8, k = widx & 255;
        float v = (k < 128) ? Wr[co * 128 + k] : Wl[co * 128 + (k - 128)];
        wct[widx] = f2b(v);
    }
    if (blockIdx.x == 0) bn[threadIdx.x] = 0.f;      // bn_sum[128] + bn_sumsq[128]
    if (blockIdx.x == 1 && threadIdx.x < 32)         // fp8 zero-row at index nNodes
        ((uint32*)(xq8))[(size_t)total8 * 2 + threadIdx.x] = 0;
}

// ---------------------------------------------------------------------------
// Chain-walk gather, 8 chains/wave, 2 VMEM wave-instrs per step (8 edges).
// R11: fp8 decode via v_cvt_pk_f32_fp8 (2 f32/instr) + float2 accumulators
// (v_pk_add_f32) -> decode+accumulate VALU instruction count halved.
__global__ __launch_bounds__(256) void sage_aggregate(
    const char* __restrict__ xq, const int* __restrict__ head,
    const int2* __restrict__ pair, uint32* __restrict__ mean_b, int nNodes)
{
    int wid = blockIdx.x * 4 + (threadIdx.x >> 6);
    int nbase = wid * 8;
    if (nbase >= nNodes) return;
    int lane = threadIdx.x & 63;
    int chain = lane >> 3;           // 0..7
    int sub = lane & 7;              // 16B slot within the 128B row

    const int ZROW = nNodes;         // zeroed fp8 row

    int cur = -1;
    if (lane < 8) {
        int n = nbase + lane;
        cur = (n < nNodes) ? head[n] : -1;
    }
    int cnt = 0;
    f32x2 acc2[8];
    #pragma unroll
    for (int i = 0; i < 8; ++i) acc2[i] = (f32x2){0.f, 0.f};

    while (__ballot(cur >= 0) != 0ULL) {
        int2 pr = make_int2(-1, ZROW);
        if (cur >= 0) pr = pair[cur];                 // 1 VMEM for 8 chains
        int s = __shfl(pr.y, chain);                  // my chain's src row
        uint4 u = *(const uint4*)(xq + ((size_t)s << 7) + sub * 16);
        #pragma unroll
        for (int w = 0; w < 4; ++w) {
            uint32 uw = (&u.x)[w];
            acc2[w * 2 + 0] += __builtin_amdgcn_cvt_pk_f32_fp8((int)uw, false);
            acc2[w * 2 + 1] += __builtin_amdgcn_cvt_pk_f32_fp8((int)uw, true);
        }
        if (cur >= 0) { ++cnt; cur = pr.x; }
    }

    int cn = __shfl(cnt, chain);
    float inv = 1.0f / fmaxf((float)cn, 1.0f);
    int n = nbase + chain;
    if (n < nNodes) {
        // 16 channels -> 32B bf16 at row n*256, offset sub*32
        uint4 o0 = make_uint4(pk2(acc2[0][0] * inv, acc2[0][1] * inv),
                              pk2(acc2[1][0] * inv, acc2[1][1] * inv),
                              pk2(acc2[2][0] * inv, acc2[2][1] * inv),
                              pk2(acc2[3][0] * inv, acc2[3][1] * inv));
        uint4 o1 = make_uint4(pk2(acc2[4][0] * inv, acc2[4][1] * inv),
                              pk2(acc2[5][0] * inv, acc2[5][1] * inv),
                              pk2(acc2[6][0] * inv, acc2[6][1] * inv),
                              pk2(acc2[7][0] * inv, acc2[7][1] * inv));
        char* base = (char*)mean_b + (size_t)n * 256 + sub * 32;
        *(uint4*)base = o0;
        *(uint4*)(base + 16) = o1;
    }
}

// ---------------------------------------------------------------------------
// h[n][co] = sum_k Xc[n][k] * WcT[co][k] + bl[co], Xc = [xb | mean_b] (K=256).
// wct staged into LDS in MFMA-fragment order; ds_read_b128 inner loop.
// R11: h stored as bf16 into ws (halved write traffic); BN partial sums
// computed from the pre-rounded f32 values.
__global__ __launch_bounds__(256) void sage_gemm(
    const ushort16* __restrict__ xb, const ushort16* __restrict__ mean_b,
    const ushort16* __restrict__ wct, const float* __restrict__ bl,
    ushort16* __restrict__ hb, float* __restrict__ bn, int nNodes)
{
    __shared__ ushort16 wsh[8 * 8 * 64 * 8];   // 64 KB, fragment-ordered
    __shared__ float redS[4][CH];
    __shared__ float redQ[4][CH];

    int tid = threadIdx.x;
    int wave = tid >> 6, lane = tid & 63;
    int col = lane & 15, kg = lane >> 4;

    #pragma unroll
    for (int it = 0; it < 16; ++it) {
        int pidx = wave * 16 + it;               // pidx = cb*8 + kstep
        int cb = pidx >> 3, ks = pidx & 7;
        bf16x8 v = *(const bf16x8*)(wct + (size_t)(cb * 16 + col) * 256 + ks * 32 + kg * 8);
        *(bf16x8*)(wsh + ((size_t)pidx * 64 + lane) * 8) = v;
    }

    int rowBase = blockIdx.x * 64 + wave * 16;
    int arow = min(rowBase + col, nNodes - 1);          // A-frag row = lane&15
    const ushort16* xrow = xb + (size_t)arow * CH;
    const ushort16* mrow = mean_b + (size_t)arow * CH;

    bf16x8 afrag[8];
    #pragma unroll
    for (int t = 0; t < 4; ++t)
        afrag[t] = *(const bf16x8*)(xrow + t * 32 + kg * 8);
    #pragma unroll
    for (int t = 0; t < 4; ++t)
        afrag[4 + t] = *(const bf16x8*)(mrow + t * 32 + kg * 8);

    __syncthreads();

    f32x4 acc[8];
    #pragma unroll
    for (int cb = 0; cb < 8; ++cb) acc[cb] = (f32x4){0.f, 0.f, 0.f, 0.f};

    #pragma unroll
    for (int kstep = 0; kstep < 8; ++kstep) {
        bf16x8 a = afrag[kstep];
        #pragma unroll
        for (int cb = 0; cb < 8; ++cb) {
            bf16x8 b = *(const bf16x8*)(wsh + ((size_t)(cb * 8 + kstep) * 64 + lane) * 8);
            acc[cb] = __builtin_amdgcn_mfma_f32_16x16x32_bf16(a, b, acc[cb], 0, 0, 0);
        }
    }

    #pragma unroll
    for (int cb = 0; cb < 8; ++cb) {
        int co = cb * 16 + col;
        float blv = bl[co];
        float s = 0.f, ss = 0.f;
        #pragma unroll
        for (int j = 0; j < 4; ++j) {
            int r = rowBase + kg * 4 + j;               // C row = (lane>>4)*4+j
            float v = acc[cb][j] + blv;
            if (r < nNodes) {
                hb[(size_t)r * CH + co] = f2b(v);
                s += v;
                ss += v * v;
            }
        }
        s  += __shfl_xor(s, 16);  s  += __shfl_xor(s, 32);
        ss += __shfl_xor(ss, 16); ss += __shfl_xor(ss, 32);
        if (kg == 0) { redS[wave][co] = s; redQ[wave][co] = ss; }
    }
    __syncthreads();
    if (tid < CH) {
        atomicAdd(&bn[tid], redS[0][tid] + redS[1][tid] + redS[2][tid] + redS[3][tid]);
    } else {
        int c = tid - CH;
        atomicAdd(&bn[CH + c], redQ[0][c] + redQ[1][c] + redQ[2][c] + redQ[3][c]);
    }
}

// ---------------------------------------------------------------------------
// Fused BN-finalize + apply: reads bf16 h (8 ch/thread), writes f32 d_out.
__global__ __launch_bounds__(256) void sage_apply(
    const ushort16* __restrict__ hb, float* __restrict__ out,
    const float* __restrict__ bn, const float* __restrict__ gamma,
    const float* __restrict__ beta, int total8, int nNodes)
{
    __shared__ float sc_sh[CH], sh_sh[CH];
    int tid = threadIdx.x;
    if (tid < CH) {
        float invN = 1.0f / (float)nNodes;
        float mu = bn[tid] * invN;
        float var = fmaxf(bn[CH + tid] * invN - mu * mu, 0.f);
        float sc = gamma[tid] * rsqrtf(var + BN_EPS);
        sc_sh[tid] = sc;
        sh_sh[tid] = beta[tid] - mu * sc;
    }
    __syncthreads();
    int i = blockIdx.x * 256 + tid;
    if (i >= total8) return;
    uint4 u = *(const uint4*)(hb + (size_t)i * 8);
    int c = (i * 8) & 127;
    float4 o0, o1;
    o0.x = fmaxf(fmaf(blo(u.x), sc_sh[c + 0], sh_sh[c + 0]), 0.f);
    o0.y = fmaxf(fmaf(bhi(u.x), sc_sh[c + 1], sh_sh[c + 1]), 0.f);
    o0.z = fmaxf(fmaf(blo(u.y), sc_sh[c + 2], sh_sh[c + 2]), 0.f);
    o0.w = fmaxf(fmaf(bhi(u.y), sc_sh[c + 3], sh_sh[c + 3]), 0.f);
    o1.x = fmaxf(fmaf(blo(u.z), sc_sh[c + 4], sh_sh[c + 4]), 0.f);
    o1.y = fmaxf(fmaf(bhi(u.z), sc_sh[c + 5], sh_sh[c + 5]), 0.f);
    o1.z = fmaxf(fmaf(blo(u.w), sc_sh[c + 6], sh_sh[c + 6]), 0.f);
    o1.w = fmaxf(fmaf(bhi(u.w), sc_sh[c + 7], sh_sh[c + 7]), 0.f);
    float4* dst = (float4*)(out + (size_t)i * 8);
    dst[0] = o0;
    dst[1] = o1;
}

// ---------------------------------------------------------------------------
extern "C" void kernel_launch(void* const* d_in, const int* in_sizes, int n_in,
                              void* d_out, int out_size, void* d_ws, size_t ws_size,
                              hipStream_t stream)
{
    const float* x     = (const float*)d_in[0];
    const void*  ei    = d_in[1];
    const float* Wl    = (const float*)d_in[2];
    const float* bl    = (const float*)d_in[3];
    const float* Wr    = (const float*)d_in[4];
    const float* gamma = (const float*)d_in[5];
    const float* beta  = (const float*)d_in[6];

    int nNodes = in_sizes[0] / CH;
    int nEdges = in_sizes[1] / 2;
    int nBlkM  = (nNodes + 63) / 64;

    // ws layout (256B-aligned slabs); ws_size = 256 MiB (observed poison fill)
    char* p = (char*)d_ws;
    auto take = [&](size_t bytes) {
        char* r = p;
        p += (bytes + 255) & ~(size_t)255;
        return r;
    };
    ushort16* xb      = (ushort16*)take((size_t)nNodes * CH * 2);      // 12.8 MB
    char*     xq      = (char*)take((size_t)nNodes * CH + 128);       // 6.4 MB fp8 + zero row
    ushort16* mean_b  = (ushort16*)take((size_t)nNodes * CH * 2);      // 12.8 MB
    ushort16* hb      = (ushort16*)take((size_t)nNodes * CH * 2);      // 12.8 MB bf16 h
    ushort16* wct     = (ushort16*)take((size_t)CH * 256 * 2);         // 64 KB
    int*      head    = (int*)take((size_t)nNodes * 4);                // memset 0xFF
    float*    bn      = (float*)take(256 * 4);                         // zeroed in prep
    int2*     pair    = (int2*)take((size_t)nEdges * 8);               // 6.4 MB

    float* out = (float*)d_out;

    hipMemsetAsync(head, 0xFF, (size_t)nNodes * 4, stream);            // head = -1

    int total8 = nNodes * CH / 8;
    int eBlocks = (nEdges + 255) / 256;
    int pBlocks = max(eBlocks, (total8 + 255) / 256);
    sage_prep<<<pBlocks, 256, 0, stream>>>(
        x, ei, Wl, Wr, head, pair, (uint32*)xb, (uint2*)xq, wct, bn,
        nEdges, total8);

    int aBlocks = (nNodes + 31) / 32;   // 8 nodes/wave, 4 waves/block
    sage_aggregate<<<aBlocks, 256, 0, stream>>>(
        xq, head, pair, (uint32*)mean_b, nNodes);

    sage_gemm<<<nBlkM, 256, 0, stream>>>(
        xb, mean_b, wct, bl, hb, bn, nNodes);

    sage_apply<<<(total8 + 255) / 256, 256, 0, stream>>>(
        hb, out, bn, gamma, beta, total8, nNodes);
}

// Round 12
// 124.027 us; speedup vs baseline: 1.5755x; 1.0045x over previous
//
#include <hip/hip_runtime.h>

#define CH 128
#define BN_EPS 1e-5f

typedef unsigned int uint32;
typedef unsigned short ushort16;
using f32x2  = __attribute__((ext_vector_type(2))) float;
using f32x4  = __attribute__((ext_vector_type(4))) float;
using bf16x8 = __attribute__((ext_vector_type(8))) short;

__device__ __forceinline__ ushort16 f2b(float f) {
    uint32 u = __float_as_uint(f);
    return (ushort16)((u + 0x7FFFu + ((u >> 16) & 1u)) >> 16);   // RNE
}
__device__ __forceinline__ uint32 pk2(float a, float b) {
    return (uint32)f2b(a) | ((uint32)f2b(b) << 16);
}
__device__ __forceinline__ float blo(uint32 u) { return __uint_as_float(u << 16); }
__device__ __forceinline__ float bhi(uint32 u) { return __uint_as_float(u & 0xFFFF0000u); }

// ---------------------------------------------------------------------------
// Pure-streaming convert kernel (no atomics — isolated from the chain build):
//  x f32 -> xb bf16 + xq fp8-e4m3; WcT bf16 build; bn zero; head = -1;
//  fp8 zero-row. All coalesced loads/stores, no divergence.
__global__ __launch_bounds__(256) void sage_convert(
    const float* __restrict__ x,
    const float* __restrict__ Wl, const float* __restrict__ Wr,
    uint32* __restrict__ xb4, uint2* __restrict__ xq8,
    ushort16* __restrict__ wct, float* __restrict__ bn,
    int* __restrict__ head, int nNodes, int total8)
{
    int idx = blockIdx.x * 256 + threadIdx.x;

    if (idx < total8) {
        const float4* x4 = (const float4*)x;
        float4 a = x4[2 * idx], b = x4[2 * idx + 1];
        uint4 o;
        o.x = pk2(a.x, a.y); o.y = pk2(a.z, a.w);
        o.z = pk2(b.x, b.y); o.w = pk2(b.z, b.w);
        ((uint4*)xb4)[idx] = o;

        int qa = __builtin_amdgcn_cvt_pk_fp8_f32(a.x, a.y, 0, false);
        qa = __builtin_amdgcn_cvt_pk_fp8_f32(a.z, a.w, qa, true);
        int qb = __builtin_amdgcn_cvt_pk_fp8_f32(b.x, b.y, 0, false);
        qb = __builtin_amdgcn_cvt_pk_fp8_f32(b.z, b.w, qb, true);
        xq8[idx] = make_uint2((uint32)qa, (uint32)qb);
    }

    if (idx < nNodes) head[idx] = -1;

    if (blockIdx.x < 128) {
        int widx = blockIdx.x * 256 + threadIdx.x;   // covers 128*256 = CH*256
        int co = widx >> 8, k = widx & 255;
        float v = (k < 128) ? Wr[co * 128 + k] : Wl[co * 128 + (k - 128)];
        wct[widx] = f2b(v);
    }
    if (blockIdx.x == 0) bn[threadIdx.x] = 0.f;      // bn_sum[128] + bn_sumsq[128]
    if (blockIdx.x == 1 && threadIdx.x < 32)         // fp8 zero-row at index nNodes
        ((uint32*)(xq8))[(size_t)total8 * 2 + threadIdx.x] = 0;
}

// ---------------------------------------------------------------------------
// Chain-build kernel (isolated atomic stream):
//  head[d] <- atomicExch, pair[e] = {next, src}.
//  int64-vs-int32 detect inline via ballot over first 64 odd words.
__global__ __launch_bounds__(256) void sage_chain(
    const void* __restrict__ ei, int* __restrict__ head,
    int2* __restrict__ pair, int nEdges)
{
    const int* pi = (const int*)ei;
    int lane = threadIdx.x & 63;
    int probe = pi[lane * 2 + 1];
    bool is64 = (__ballot(probe != 0) == 0ULL);

    int e = blockIdx.x * 256 + threadIdx.x;
    if (e >= nEdges) return;
    int s, d;
    if (is64) {
        const long long* p = (const long long*)ei;
        s = (int)p[e];
        d = (int)p[nEdges + e];
    } else {
        s = pi[e];
        d = pi[nEdges + e];
    }
    int old = atomicExch(&head[d], e);
    pair[e] = make_int2(old, s);
}

// ---------------------------------------------------------------------------
// Chain-walk gather, 8 chains/wave, 2 VMEM wave-instrs per step (8 edges).
// fp8 decode via v_cvt_pk_f32_fp8 + float2 accumulators.
__global__ __launch_bounds__(256) void sage_aggregate(
    const char* __restrict__ xq, const int* __restrict__ head,
    const int2* __restrict__ pair, uint32* __restrict__ mean_b, int nNodes)
{
    int wid = blockIdx.x * 4 + (threadIdx.x >> 6);
    int nbase = wid * 8;
    if (nbase >= nNodes) return;
    int lane = threadIdx.x & 63;
    int chain = lane >> 3;           // 0..7
    int sub = lane & 7;              // 16B slot within the 128B row

    const int ZROW = nNodes;         // zeroed fp8 row

    int cur = -1;
    if (lane < 8) {
        int n = nbase + lane;
        cur = (n < nNodes) ? head[n] : -1;
    }
    int cnt = 0;
    f32x2 acc2[8];
    #pragma unroll
    for (int i = 0; i < 8; ++i) acc2[i] = (f32x2){0.f, 0.f};

    while (__ballot(cur >= 0) != 0ULL) {
        int2 pr = make_int2(-1, ZROW);
        if (cur >= 0) pr = pair[cur];                 // 1 VMEM for 8 chains
        int s = __shfl(pr.y, chain);                  // my chain's src row
        uint4 u = *(const uint4*)(xq + ((size_t)s << 7) + sub * 16);
        #pragma unroll
        for (int w = 0; w < 4; ++w) {
            uint32 uw = (&u.x)[w];
            acc2[w * 2 + 0] += __builtin_amdgcn_cvt_pk_f32_fp8((int)uw, false);
            acc2[w * 2 + 1] += __builtin_amdgcn_cvt_pk_f32_fp8((int)uw, true);
        }
        if (cur >= 0) { ++cnt; cur = pr.x; }
    }

    int cn = __shfl(cnt, chain);
    float inv = 1.0f / fmaxf((float)cn, 1.0f);
    int n = nbase + chain;
    if (n < nNodes) {
        uint4 o0 = make_uint4(pk2(acc2[0][0] * inv, acc2[0][1] * inv),
                              pk2(acc2[1][0] * inv, acc2[1][1] * inv),
                              pk2(acc2[2][0] * inv, acc2[2][1] * inv),
                              pk2(acc2[3][0] * inv, acc2[3][1] * inv));
        uint4 o1 = make_uint4(pk2(acc2[4][0] * inv, acc2[4][1] * inv),
                              pk2(acc2[5][0] * inv, acc2[5][1] * inv),
                              pk2(acc2[6][0] * inv, acc2[6][1] * inv),
                              pk2(acc2[7][0] * inv, acc2[7][1] * inv));
        char* base = (char*)mean_b + (size_t)n * 256 + sub * 32;
        *(uint4*)base = o0;
        *(uint4*)(base + 16) = o1;
    }
}

// ---------------------------------------------------------------------------
// h[n][co] = sum_k Xc[n][k] * WcT[co][k] + bl[co], Xc = [xb | mean_b] (K=256).
// wct staged into LDS in MFMA-fragment order; ds_read_b128 inner loop.
// h stored as bf16; BN partials from pre-rounded f32 -> one atomic/ch/block.
__global__ __launch_bounds__(256) void sage_gemm(
    const ushort16* __restrict__ xb, const ushort16* __restrict__ mean_b,
    const ushort16* __restrict__ wct, const float* __restrict__ bl,
    ushort16* __restrict__ hb, float* __restrict__ bn, int nNodes)
{
    __shared__ ushort16 wsh[8 * 8 * 64 * 8];   // 64 KB, fragment-ordered
    __shared__ float redS[4][CH];
    __shared__ float redQ[4][CH];

    int tid = threadIdx.x;
    int wave = tid >> 6, lane = tid & 63;
    int col = lane & 15, kg = lane >> 4;

    #pragma unroll
    for (int it = 0; it < 16; ++it) {
        int pidx = wave * 16 + it;               // pidx = cb*8 + kstep
        int cb = pidx >> 3, ks = pidx & 7;
        bf16x8 v = *(const bf16x8*)(wct + (size_t)(cb * 16 + col) * 256 + ks * 32 + kg * 8);
        *(bf16x8*)(wsh + ((size_t)pidx * 64 + lane) * 8) = v;
    }

    int rowBase = blockIdx.x * 64 + wave * 16;
    int arow = min(rowBase + col, nNodes - 1);          // A-frag row = lane&15
    const ushort16* xrow = xb + (size_t)arow * CH;
    const ushort16* mrow = mean_b + (size_t)arow * CH;

    bf16x8 afrag[8];
    #pragma unroll
    for (int t = 0; t < 4; ++t)
        afrag[t] = *(const bf16x8*)(xrow + t * 32 + kg * 8);
    #pragma unroll
    for (int t = 0; t < 4; ++t)
        afrag[4 + t] = *(const bf16x8*)(mrow + t * 32 + kg * 8);

    __syncthreads();

    f32x4 acc[8];
    #pragma unroll
    for (int cb = 0; cb < 8; ++cb) acc[cb] = (f32x4){0.f, 0.f, 0.f, 0.f};

    #pragma unroll
    for (int kstep = 0; kstep < 8; ++kstep) {
        bf16x8 a = afrag[kstep];
        #pragma unroll
        for (int cb = 0; cb < 8; ++cb) {
            bf16x8 b = *(const bf16x8*)(wsh + ((size_t)(cb * 8 + kstep) * 64 + lane) * 8);
            acc[cb] = __builtin_amdgcn_mfma_f32_16x16x32_bf16(a, b, acc[cb], 0, 0, 0);
        }
    }

    #pragma unroll
    for (int cb = 0; cb < 8; ++cb) {
        int co = cb * 16 + col;
        float blv = bl[co];
        float s = 0.f, ss = 0.f;
        #pragma unroll
        for (int j = 0; j < 4; ++j) {
            int r = rowBase + kg * 4 + j;               // C row = (lane>>4)*4+j
            float v = acc[cb][j] + blv;
            if (r < nNodes) {
                hb[(size_t)r * CH + co] = f2b(v);
                s += v;
                ss += v * v;
            }
        }
        s  += __shfl_xor(s, 16);  s  += __shfl_xor(s, 32);
        ss += __shfl_xor(ss, 16); ss += __shfl_xor(ss, 32);
        if (kg == 0) { redS[wave][co] = s; redQ[wave][co] = ss; }
    }
    __syncthreads();
    if (tid < CH) {
        atomicAdd(&bn[tid], redS[0][tid] + redS[1][tid] + redS[2][tid] + redS[3][tid]);
    } else {
        int c = tid - CH;
        atomicAdd(&bn[CH + c], redQ[0][c] + redQ[1][c] + redQ[2][c] + redQ[3][c]);
    }
}

// ---------------------------------------------------------------------------
// Fused BN-finalize + apply: reads bf16 h (8 ch/thread), writes f32 d_out.
__global__ __launch_bounds__(256) void sage_apply(
    const ushort16* __restrict__ hb, float* __restrict__ out,
    const float* __restrict__ bn, const float* __restrict__ gamma,
    const float* __restrict__ beta, int total8, int nNodes)
{
    __shared__ float sc_sh[CH], sh_sh[CH];
    int tid = threadIdx.x;
    if (tid < CH) {
        float invN = 1.0f / (float)nNodes;
        float mu = bn[tid] * invN;
        float var = fmaxf(bn[CH + tid] * invN - mu * mu, 0.f);
        float sc = gamma[tid] * rsqrtf(var + BN_EPS);
        sc_sh[tid] = sc;
        sh_sh[tid] = beta[tid] - mu * sc;
    }
    __syncthreads();
    int i = blockIdx.x * 256 + tid;
    if (i >= total8) return;
    uint4 u = *(const uint4*)(hb + (size_t)i * 8);
    int c = (i * 8) & 127;
    float4 o0, o1;
    o0.x = fmaxf(fmaf(blo(u.x), sc_sh[c + 0], sh_sh[c + 0]), 0.f);
    o0.y = fmaxf(fmaf(bhi(u.x), sc_sh[c + 1], sh_sh[c + 1]), 0.f);
    o0.z = fmaxf(fmaf(blo(u.y), sc_sh[c + 2], sh_sh[c + 2]), 0.f);
    o0.w = fmaxf(fmaf(bhi(u.y), sc_sh[c + 3], sh_sh[c + 3]), 0.f);
    o1.x = fmaxf(fmaf(blo(u.z), sc_sh[c + 4], sh_sh[c + 4]), 0.f);
    o1.y = fmaxf(fmaf(bhi(u.z), sc_sh[c + 5], sh_sh[c + 5]), 0.f);
    o1.z = fmaxf(fmaf(blo(u.w), sc_sh[c + 6], sh_sh[c + 6]), 0.f);
    o1.w = fmaxf(fmaf(bhi(u.w), sc_sh[c + 7], sh_sh[c + 7]), 0.f);
    float4* dst = (float4*)(out + (size_t)i * 8);
    dst[0] = o0;
    dst[1] = o1;
}

// ---------------------------------------------------------------------------
extern "C" void kernel_launch(void* const* d_in, const int* in_sizes, int n_in,
                              void* d_out, int out_size, void* d_ws, size_t ws_size,
                              hipStream_t stream)
{
    const float* x     = (const float*)d_in[0];
    const void*  ei    = d_in[1];
    const float* Wl    = (const float*)d_in[2];
    const float* bl    = (const float*)d_in[3];
    const float* Wr    = (const float*)d_in[4];
    const float* gamma = (const float*)d_in[5];
    const float* beta  = (const float*)d_in[6];

    int nNodes = in_sizes[0] / CH;
    int nEdges = in_sizes[1] / 2;
    int nBlkM  = (nNodes + 63) / 64;

    // ws layout (256B-aligned slabs); ws_size = 256 MiB
    char* p = (char*)d_ws;
    auto take = [&](size_t bytes) {
        char* r = p;
        p += (bytes + 255) & ~(size_t)255;
        return r;
    };
    ushort16* xb      = (ushort16*)take((size_t)nNodes * CH * 2);      // 12.8 MB
    char*     xq      = (char*)take((size_t)nNodes * CH + 128);       // 6.4 MB fp8 + zero row
    ushort16* mean_b  = (ushort16*)take((size_t)nNodes * CH * 2);      // 12.8 MB
    ushort16* hb      = (ushort16*)take((size_t)nNodes * CH * 2);      // 12.8 MB bf16 h
    ushort16* wct     = (ushort16*)take((size_t)CH * 256 * 2);         // 64 KB
    int*      head    = (int*)take((size_t)nNodes * 4);                // init in convert
    float*    bn      = (float*)take(256 * 4);                         // zeroed in convert
    int2*     pair    = (int2*)take((size_t)nEdges * 8);               // 6.4 MB

    float* out = (float*)d_out;

    int total8 = nNodes * CH / 8;
    int eBlocks = (nEdges + 255) / 256;
    int cBlocks = max((total8 + 255) / 256, (nNodes + 255) / 256);

    sage_convert<<<cBlocks, 256, 0, stream>>>(
        x, Wl, Wr, (uint32*)xb, (uint2*)xq, wct, bn, head, nNodes, total8);

    sage_chain<<<eBlocks, 256, 0, stream>>>(ei, head, pair, nEdges);

    int aBlocks = (nNodes + 31) / 32;   // 8 nodes/wave, 4 waves/block
    sage_aggregate<<<aBlocks, 256, 0, stream>>>(
        xq, head, pair, (uint32*)mean_b, nNodes);

    sage_gemm<<<nBlkM, 256, 0, stream>>>(
        xb, mean_b, wct, bl, hb, bn, nNodes);

    sage_apply<<<(total8 + 255) / 256, 256, 0, stream>>>(
        hb, out, bn, gamma, beta, total8, nNodes);
}

// Round 13
// 115.885 us; speedup vs baseline: 1.6862x; 1.0703x over previous
//
#include <hip/hip_runtime.h>

#define CH 128
#define BN_EPS 1e-5f

typedef unsigned int uint32;
typedef unsigned short ushort16;
using f32x2  = __attribute__((ext_vector_type(2))) float;
using f32x4  = __attribute__((ext_vector_type(4))) float;
using bf16x8 = __attribute__((ext_vector_type(8))) short;

__device__ __forceinline__ ushort16 f2b(float f) {
    uint32 u = __float_as_uint(f);
    return (ushort16)((u + 0x7FFFu + ((u >> 16) & 1u)) >> 16);   // RNE
}
__device__ __forceinline__ uint32 pk2(float a, float b) {
    return (uint32)f2b(a) | ((uint32)f2b(b) << 16);
}
__device__ __forceinline__ float blo(uint32 u) { return __uint_as_float(u << 16); }
__device__ __forceinline__ float bhi(uint32 u) { return __uint_as_float(u & 0xFFFF0000u); }

// ---------------------------------------------------------------------------
// Fused prep (grid = 3125 x 256): chain-build + converts overlap (atomic
// stream hides under streaming loads/stores; proven-equivalent to split).
//  (a) head[d] <- atomicExch, pair[e] = {next, src}; x-loads hoisted above
//  (b) x f32 -> xb bf16 + xq fp8-e4m3
//  (c) blocks [0,128): WcT bf16   (d) head=-1 init, bn zero, fp8 zero-row
__global__ __launch_bounds__(256) void sage_prep(
    const float* __restrict__ x, const void* __restrict__ ei,
    const float* __restrict__ Wl, const float* __restrict__ Wr,
    int* __restrict__ head, int2* __restrict__ pair,
    uint32* __restrict__ xb4, uint2* __restrict__ xq8,
    ushort16* __restrict__ wct, float* __restrict__ bn,
    int nEdges, int nNodes, int total8)
{
    const int* pi = (const int*)ei;
    int lane = threadIdx.x & 63;
    int probe = pi[lane * 2 + 1];
    bool is64 = (__ballot(probe != 0) == 0ULL);

    int idx = blockIdx.x * 256 + threadIdx.x;

    // hoisted convert-loads (fly during the atomic round-trip)
    const float4* x4 = (const float4*)x;
    float4 a = make_float4(0, 0, 0, 0), b = make_float4(0, 0, 0, 0);
    bool hasC = (idx < total8);
    if (hasC) { a = x4[2 * idx]; b = x4[2 * idx + 1]; }

    if (idx < nEdges) {
        int s, d;
        if (is64) {
            const long long* p = (const long long*)ei;
            s = (int)p[idx];
            d = (int)p[nEdges + idx];
        } else {
            s = pi[idx];
            d = pi[nEdges + idx];
        }
        int old = atomicExch(&head[d], idx);
        pair[idx] = make_int2(old, s);
    }

    if (hasC) {
        uint4 o;
        o.x = pk2(a.x, a.y); o.y = pk2(a.z, a.w);
        o.z = pk2(b.x, b.y); o.w = pk2(b.z, b.w);
        ((uint4*)xb4)[idx] = o;

        int qa = __builtin_amdgcn_cvt_pk_fp8_f32(a.x, a.y, 0, false);
        qa = __builtin_amdgcn_cvt_pk_fp8_f32(a.z, a.w, qa, true);
        int qb = __builtin_amdgcn_cvt_pk_fp8_f32(b.x, b.y, 0, false);
        qb = __builtin_amdgcn_cvt_pk_fp8_f32(b.z, b.w, qb, true);
        xq8[idx] = make_uint2((uint32)qa, (uint32)qb);
    }

    if (blockIdx.x < 128) {
        int widx = blockIdx.x * 256 + threadIdx.x;   // covers 128*256 = CH*256
        int co = widx >> 8, k = widx & 255;
        float v = (k < 128) ? Wr[co * 128 + k] : Wl[co * 128 + (k - 128)];
        wct[widx] = f2b(v);
    }
    if (blockIdx.x == 0) bn[threadIdx.x] = 0.f;
    if (blockIdx.x == 1 && threadIdx.x < 32)         // fp8 zero-row at index nNodes
        ((uint32*)(xq8))[(size_t)total8 * 2 + threadIdx.x] = 0;
}

// NOTE: head init moved to a tiny standalone kernel so prep's chain-build can
// run in the same dispatch only AFTER init. We fold init into... a separate
// 196-block kernel is cheap (<2us) and keeps the dependency correct.
__global__ __launch_bounds__(256) void sage_init(int* __restrict__ head, int nNodes) {
    int i = blockIdx.x * 256 + threadIdx.x;
    if (i < nNodes) head[i] = -1;
}

// ---------------------------------------------------------------------------
// Chain-walk gather, 8 chains/wave, 2 VMEM/step (8 edges), fp8 rows.
// R13: software-pipelined — next pair[] load issues BEFORE the row gathers,
// overlapping the serial next-pointer latency with row fetch + decode.
__global__ __launch_bounds__(256) void sage_aggregate(
    const char* __restrict__ xq, const int* __restrict__ head,
    const int2* __restrict__ pair, uint32* __restrict__ mean_b, int nNodes)
{
    int wid = blockIdx.x * 4 + (threadIdx.x >> 6);
    int nbase = wid * 8;
    if (nbase >= nNodes) return;
    int lane = threadIdx.x & 63;
    int chain = lane >> 3;           // 0..7
    int sub = lane & 7;              // 16B slot within the 128B row

    const int ZROW = nNodes;         // zeroed fp8 row

    int cur = -1;
    if (lane < 8) {
        int n = nbase + lane;
        cur = (n < nNodes) ? head[n] : -1;
    }
    int cnt = 0;
    f32x2 acc2[8];
    #pragma unroll
    for (int i = 0; i < 8; ++i) acc2[i] = (f32x2){0.f, 0.f};

    int2 pr = make_int2(-1, ZROW);
    if (cur >= 0) pr = pair[cur];

    while (__ballot(cur >= 0) != 0ULL) {
        // prefetch next pair entry (overlaps with row gather below)
        int nxt = pr.x;
        int2 prn = make_int2(-1, ZROW);
        if (cur >= 0 && nxt >= 0) prn = pair[nxt];

        int s = __shfl(pr.y, chain);                  // my chain's src row
        uint4 u = *(const uint4*)(xq + ((size_t)s << 7) + sub * 16);
        #pragma unroll
        for (int w = 0; w < 4; ++w) {
            uint32 uw = (&u.x)[w];
            acc2[w * 2 + 0] += __builtin_amdgcn_cvt_pk_f32_fp8((int)uw, false);
            acc2[w * 2 + 1] += __builtin_amdgcn_cvt_pk_f32_fp8((int)uw, true);
        }
        if (cur >= 0) { ++cnt; cur = nxt; }
        pr = prn;
    }

    int cn = __shfl(cnt, chain);
    float inv = 1.0f / fmaxf((float)cn, 1.0f);
    int n = nbase + chain;
    if (n < nNodes) {
        uint4 o0 = make_uint4(pk2(acc2[0][0] * inv, acc2[0][1] * inv),
                              pk2(acc2[1][0] * inv, acc2[1][1] * inv),
                              pk2(acc2[2][0] * inv, acc2[2][1] * inv),
                              pk2(acc2[3][0] * inv, acc2[3][1] * inv));
        uint4 o1 = make_uint4(pk2(acc2[4][0] * inv, acc2[4][1] * inv),
                              pk2(acc2[5][0] * inv, acc2[5][1] * inv),
                              pk2(acc2[6][0] * inv, acc2[6][1] * inv),
                              pk2(acc2[7][0] * inv, acc2[7][1] * inv));
        char* base = (char*)mean_b + (size_t)n * 256 + sub * 32;
        *(uint4*)base = o0;
        *(uint4*)(base + 16) = o1;
    }
}

// ---------------------------------------------------------------------------
// GEMM, R13: 128 rows per block (two 16-row tiles per wave). Staged 64KB W
// serves 2x rows; each ds_read_b128 feeds TWO MFMAs; per-block fixed costs
// (staging, barriers, BN atomics) halve. 391 blocks.
__global__ __launch_bounds__(256) void sage_gemm(
    const ushort16* __restrict__ xb, const ushort16* __restrict__ mean_b,
    const ushort16* __restrict__ wct, const float* __restrict__ bl,
    ushort16* __restrict__ hb, float* __restrict__ bn, int nNodes)
{
    __shared__ ushort16 wsh[8 * 8 * 64 * 8];   // 64 KB, fragment-ordered
    __shared__ float redS[4][CH];
    __shared__ float redQ[4][CH];

    int tid = threadIdx.x;
    int wave = tid >> 6, lane = tid & 63;
    int col = lane & 15, kg = lane >> 4;

    #pragma unroll
    for (int it = 0; it < 16; ++it) {
        int pidx = wave * 16 + it;               // pidx = cb*8 + kstep
        int cb = pidx >> 3, ks = pidx & 7;
        bf16x8 v = *(const bf16x8*)(wct + (size_t)(cb * 16 + col) * 256 + ks * 32 + kg * 8);
        *(bf16x8*)(wsh + ((size_t)pidx * 64 + lane) * 8) = v;
    }

    int row0 = blockIdx.x * 128 + wave * 16;            // tile 0
    int row1 = row0 + 64;                               // tile 1
    int arow0 = min(row0 + col, nNodes - 1);
    int arow1 = min(row1 + col, nNodes - 1);
    const ushort16* xr0 = xb + (size_t)arow0 * CH;
    const ushort16* mr0 = mean_b + (size_t)arow0 * CH;
    const ushort16* xr1 = xb + (size_t)arow1 * CH;
    const ushort16* mr1 = mean_b + (size_t)arow1 * CH;

    bf16x8 af0[8], af1[8];
    #pragma unroll
    for (int t = 0; t < 4; ++t) {
        af0[t]     = *(const bf16x8*)(xr0 + t * 32 + kg * 8);
        af0[4 + t] = *(const bf16x8*)(mr0 + t * 32 + kg * 8);
        af1[t]     = *(const bf16x8*)(xr1 + t * 32 + kg * 8);
        af1[4 + t] = *(const bf16x8*)(mr1 + t * 32 + kg * 8);
    }

    __syncthreads();

    f32x4 acc0[8], acc1[8];
    #pragma unroll
    for (int cb = 0; cb < 8; ++cb) {
        acc0[cb] = (f32x4){0.f, 0.f, 0.f, 0.f};
        acc1[cb] = (f32x4){0.f, 0.f, 0.f, 0.f};
    }

    #pragma unroll
    for (int kstep = 0; kstep < 8; ++kstep) {
        #pragma unroll
        for (int cb = 0; cb < 8; ++cb) {
            bf16x8 b = *(const bf16x8*)(wsh + ((size_t)(cb * 8 + kstep) * 64 + lane) * 8);
            acc0[cb] = __builtin_amdgcn_mfma_f32_16x16x32_bf16(af0[kstep], b, acc0[cb], 0, 0, 0);
            acc1[cb] = __builtin_amdgcn_mfma_f32_16x16x32_bf16(af1[kstep], b, acc1[cb], 0, 0, 0);
        }
    }

    #pragma unroll
    for (int cb = 0; cb < 8; ++cb) {
        int co = cb * 16 + col;
        float blv = bl[co];
        float s = 0.f, ss = 0.f;
        #pragma unroll
        for (int j = 0; j < 4; ++j) {
            int r0 = row0 + kg * 4 + j;                 // C row = (lane>>4)*4+j
            float v0 = acc0[cb][j] + blv;
            if (r0 < nNodes) {
                hb[(size_t)r0 * CH + co] = f2b(v0);
                s += v0; ss += v0 * v0;
            }
            int r1 = row1 + kg * 4 + j;
            float v1 = acc1[cb][j] + blv;
            if (r1 < nNodes) {
                hb[(size_t)r1 * CH + co] = f2b(v1);
                s += v1; ss += v1 * v1;
            }
        }
        s  += __shfl_xor(s, 16);  s  += __shfl_xor(s, 32);
        ss += __shfl_xor(ss, 16); ss += __shfl_xor(ss, 32);
        if (kg == 0) { redS[wave][co] = s; redQ[wave][co] = ss; }
    }
    __syncthreads();
    if (tid < CH) {
        atomicAdd(&bn[tid], redS[0][tid] + redS[1][tid] + redS[2][tid] + redS[3][tid]);
    } else {
        int c = tid - CH;
        atomicAdd(&bn[CH + c], redQ[0][c] + redQ[1][c] + redQ[2][c] + redQ[3][c]);
    }
}

// ---------------------------------------------------------------------------
// Fused BN-finalize + apply: reads bf16 h (8 ch/thread), writes f32 d_out.
__global__ __launch_bounds__(256) void sage_apply(
    const ushort16* __restrict__ hb, float* __restrict__ out,
    const float* __restrict__ bn, const float* __restrict__ gamma,
    const float* __restrict__ beta, int total8, int nNodes)
{
    __shared__ float sc_sh[CH], sh_sh[CH];
    int tid = threadIdx.x;
    if (tid < CH) {
        float invN = 1.0f / (float)nNodes;
        float mu = bn[tid] * invN;
        float var = fmaxf(bn[CH + tid] * invN - mu * mu, 0.f);
        float sc = gamma[tid] * rsqrtf(var + BN_EPS);
        sc_sh[tid] = sc;
        sh_sh[tid] = beta[tid] - mu * sc;
    }
    __syncthreads();
    int i = blockIdx.x * 256 + tid;
    if (i >= total8) return;
    uint4 u = *(const uint4*)(hb + (size_t)i * 8);
    int c = (i * 8) & 127;
    float4 o0, o1;
    o0.x = fmaxf(fmaf(blo(u.x), sc_sh[c + 0], sh_sh[c + 0]), 0.f);
    o0.y = fmaxf(fmaf(bhi(u.x), sc_sh[c + 1], sh_sh[c + 1]), 0.f);
    o0.z = fmaxf(fmaf(blo(u.y), sc_sh[c + 2], sh_sh[c + 2]), 0.f);
    o0.w = fmaxf(fmaf(bhi(u.y), sc_sh[c + 3], sh_sh[c + 3]), 0.f);
    o1.x = fmaxf(fmaf(blo(u.z), sc_sh[c + 4], sh_sh[c + 4]), 0.f);
    o1.y = fmaxf(fmaf(bhi(u.z), sc_sh[c + 5], sh_sh[c + 5]), 0.f);
    o1.z = fmaxf(fmaf(blo(u.w), sc_sh[c + 6], sh_sh[c + 6]), 0.f);
    o1.w = fmaxf(fmaf(bhi(u.w), sc_sh[c + 7], sh_sh[c + 7]), 0.f);
    float4* dst = (float4*)(out + (size_t)i * 8);
    dst[0] = o0;
    dst[1] = o1;
}

// ---------------------------------------------------------------------------
extern "C" void kernel_launch(void* const* d_in, const int* in_sizes, int n_in,
                              void* d_out, int out_size, void* d_ws, size_t ws_size,
                              hipStream_t stream)
{
    const float* x     = (const float*)d_in[0];
    const void*  ei    = d_in[1];
    const float* Wl    = (const float*)d_in[2];
    const float* bl    = (const float*)d_in[3];
    const float* Wr    = (const float*)d_in[4];
    const float* gamma = (const float*)d_in[5];
    const float* beta  = (const float*)d_in[6];

    int nNodes = in_sizes[0] / CH;
    int nEdges = in_sizes[1] / 2;
    int nBlkM  = (nNodes + 127) / 128;

    // ws layout (256B-aligned slabs); ws_size = 256 MiB
    char* p = (char*)d_ws;
    auto take = [&](size_t bytes) {
        char* r = p;
        p += (bytes + 255) & ~(size_t)255;
        return r;
    };
    ushort16* xb      = (ushort16*)take((size_t)nNodes * CH * 2);      // 12.8 MB
    char*     xq      = (char*)take((size_t)nNodes * CH + 128);       // 6.4 MB fp8 + zero row
    ushort16* mean_b  = (ushort16*)take((size_t)nNodes * CH * 2);      // 12.8 MB
    ushort16* hb      = (ushort16*)take((size_t)nNodes * CH * 2);      // 12.8 MB bf16 h
    ushort16* wct     = (ushort16*)take((size_t)CH * 256 * 2);         // 64 KB
    int*      head    = (int*)take((size_t)nNodes * 4);                // init kernel
    float*    bn      = (float*)take(256 * 4);                         // zeroed in prep
    int2*     pair    = (int2*)take((size_t)nEdges * 8);               // 6.4 MB

    float* out = (float*)d_out;

    int total8 = nNodes * CH / 8;
    int eBlocks = (nEdges + 255) / 256;
    int pBlocks = max(eBlocks, (total8 + 255) / 256);

    sage_init<<<(nNodes + 255) / 256, 256, 0, stream>>>(head, nNodes);

    sage_prep<<<pBlocks, 256, 0, stream>>>(
        x, ei, Wl, Wr, head, pair, (uint32*)xb, (uint2*)xq, wct, bn,
        nEdges, nNodes, total8);

    int aBlocks = (nNodes + 31) / 32;   // 8 nodes/wave, 4 waves/block
    sage_aggregate<<<aBlocks, 256, 0, stream>>>(
        xq, head, pair, (uint32*)mean_b, nNodes);

    sage_gemm<<<nBlkM, 256, 0, stream>>>(
        xb, mean_b, wct, bl, hb, bn, nNodes);

    sage_apply<<<(total8 + 255) / 256, 256, 0, stream>>>(
        hb, out, bn, gamma, beta, total8, nNodes);
}